// Round 5
// baseline (602.202 us; speedup 1.0000x reference)
//
#include <hip/hip_runtime.h>
#include <math.h>

typedef unsigned short u16;
typedef __attribute__((ext_vector_type(8))) short bf16x8;
typedef __attribute__((ext_vector_type(4))) float f32x4;

#define MFMA16(a, b, c) __builtin_amdgcn_mfma_f32_16x16x32_bf16((a), (b), (c), 0, 0, 0)

__device__ __forceinline__ u16 f2bf(float f) {
    union { float f; unsigned u; } v; v.f = f;
    unsigned u = v.u;
    unsigned r = (u + 0x7FFFu + ((u >> 16) & 1u)) >> 16;
    return (u16)r;
}

// pack two floats -> (bf16(hi)<<16)|bf16(lo), round-half-up, one v_perm_b32
__device__ __forceinline__ unsigned pack_bf16(float lo, float hi) {
    union { float f; unsigned u; } a, b; a.f = lo; b.f = hi;
    return __builtin_amdgcn_perm(b.u + 0x8000u, a.u + 0x8000u, 0x07060302u);
}

__device__ __forceinline__ float fexp2(float x) {
#if __has_builtin(__builtin_amdgcn_exp2f)
    return __builtin_amdgcn_exp2f(x);
#else
    return __expf(x * 0.6931471805599453f);
#endif
}

// async 16B/lane global->LDS DMA. LDS dest must be lane-linear (base + lane*16).
__device__ __forceinline__ void gl_lds16(const u16* g, u16* l) {
    __builtin_amdgcn_global_load_lds(
        (const __attribute__((address_space(1))) unsigned*)g,
        (__attribute__((address_space(3))) unsigned*)l, 16, 0, 0);
}

// -------- all-weights transpose + fp32->bf16 convert, single dispatch --------
__global__ __launch_bounds__(256) void transpose_cvt_all(
    const float* __restrict__ Wq, const float* __restrict__ Wk,
    const float* __restrict__ Wv, const float* __restrict__ Wo,
    const float* __restrict__ W1, const float* __restrict__ W2,
    u16* __restrict__ wqt, u16* __restrict__ wkt, u16* __restrict__ wvt,
    u16* __restrict__ wot, u16* __restrict__ w1t, u16* __restrict__ w2t)
{
    __shared__ float tile[64][65];
    int fb = blockIdx.x;
    const float* src; u16* dst; int K, N, bx, by;
    if (fb < 256) {
        int w = fb >> 6, b = fb & 63;
        src = (w == 0) ? Wq : (w == 1) ? Wk : (w == 2) ? Wv : Wo;
        dst = (w == 0) ? wqt : (w == 1) ? wkt : (w == 2) ? wvt : wot;
        K = 512; N = 512; bx = b & 7; by = b >> 3;
    } else if (fb < 512) {
        int b = fb - 256; src = W1; dst = w1t; K = 512; N = 2048; bx = b & 31; by = b >> 5;
    } else {
        int b = fb - 512; src = W2; dst = w2t; K = 2048; N = 512; bx = b & 7; by = b >> 3;
    }
    int n0 = bx * 64, k0 = by * 64;
    int tx = threadIdx.x & 63, ty = threadIdx.x >> 6;
    #pragma unroll
    for (int i = ty; i < 64; i += 4)
        tile[i][tx] = src[(size_t)(k0 + i) * N + n0 + tx];
    __syncthreads();
    #pragma unroll
    for (int i = ty; i < 64; i += 4)
        dst[(size_t)(n0 + i) * K + k0 + tx] = f2bf(tile[tx][i]);
}

// ---------------- layernorm: fp32 in -> bf16 out, rows of 512 ----------------
__global__ __launch_bounds__(256) void ln_kernel(const float* __restrict__ in,
                                                 u16* __restrict__ out,
                                                 const float* __restrict__ g,
                                                 const float* __restrict__ b) {
    int row = blockIdx.x;
    const float* rp = in + (size_t)row * 512;
    int t = threadIdx.x;
    float2 v = *(const float2*)(rp + t * 2);
    float s = v.x + v.y;
    float sq = v.x * v.x + v.y * v.y;
    #pragma unroll
    for (int off = 32; off > 0; off >>= 1) {
        s  += __shfl_down(s, off, 64);
        sq += __shfl_down(sq, off, 64);
    }
    __shared__ float red[8];
    __shared__ float stat[2];
    int wid = t >> 6;
    if ((t & 63) == 0) { red[wid] = s; red[wid + 4] = sq; }
    __syncthreads();
    if (t == 0) {
        float S = red[0] + red[1] + red[2] + red[3];
        float Q = red[4] + red[5] + red[6] + red[7];
        float mu = S * (1.0f / 512.0f);
        float var = Q * (1.0f / 512.0f) - mu * mu;
        stat[0] = mu;
        stat[1] = rsqrtf(var + 1e-5f);
    }
    __syncthreads();
    float mu = stat[0], inv = stat[1];
    int c = t * 2;
    float2 gv = *(const float2*)(g + c);
    float2 bv = *(const float2*)(b + c);
    ushort2 ov;
    ov.x = f2bf((v.x - mu) * inv * gv.x + bv.x);
    ov.y = f2bf((v.y - mu) * inv * gv.y + bv.y);
    *(ushort2*)(out + (size_t)row * 512 + c) = ov;
}

// ================== 256x256 8-phase MFMA GEMM machinery ======================
// BM=BN=256, BK=64, 512 threads = 8 waves (2M x 4N), per-wave out 128x64.
// LDS 128 KiB STATIC: [buf2][A/B][region2][128x64 bf16]. XOR-swizzle
// byte^=(row&7)<<4 via inverse-swizzled GLOBAL source + swizzled ds_read.
// REGION SEMANTICS (round-3/4 post-mortem): stA(u,hf) writes the WHOLE
// 128-row region hf, and the wm_=hf waves read that region in ALL FOUR
// phases (rows 0-63 at ph0/ph1, rows 64-127 at ph2/ph3).  So A regions may
// only be staged at ph0/ph1 (1-step-ahead, opposite buf, readers finished
// at previous step's end barrier).  B regions are fully read by end of ph1
// (k0 at ph0, k1 at ph1), so B stages 2-steps-ahead at ph2/ph3.
// Reads balanced 8/8/4/4.  lgkmcnt(0) AFTER each MFMA cluster (before
// barrier #2): MFMAs use compiler-counted waits (reads stream under them),
// while the pre-barrier drain keeps the cross-wave WAR guarantee.
// vmcnt(4) at step end retires tile s+1 (queue B(s+1)·A(s+1)·B(s+2));
// vmcnt(0) on the last two steps.

#define FENCE() asm volatile("" ::: "memory")
#define BARF()  do { FENCE(); __builtin_amdgcn_s_barrier(); FENCE(); } while (0)
#define LGKM0() asm volatile("s_waitcnt lgkmcnt(0)" ::: "memory")
#define VM4()   asm volatile("s_waitcnt vmcnt(4)" ::: "memory")
#define VM0()   asm volatile("s_waitcnt vmcnt(0)" ::: "memory")
#define PRIO1() __builtin_amdgcn_s_setprio(1)
#define PRIO0() __builtin_amdgcn_s_setprio(0)

// swizzled fragment read: region is [128 rows][64 bf16], 16B-aligned groups
__device__ __forceinline__ bf16x8 ldfrag(const u16* __restrict__ base, int R, int ko, int lq) {
    int o = (ko + lq * 8) ^ ((R & 7) * 8);
    return *(const bf16x8*)(base + R * 64 + o);
}

__device__ __forceinline__ void gemm256_core(
    const u16* __restrict__ A, const u16* __restrict__ Bt, int K,
    int m0, int n0, int t, u16* __restrict__ smem, f32x4 (&acc)[8][4])
{
    const int NS = K >> 6;
    const int wid = t >> 6, lane = t & 63;
    const int lm = lane & 15, lq = lane >> 4;
    const int wm_ = wid >> 2;            // warp_m: A region
    const int wn_ = wid & 3;             // warp_n
    const int wbh = wn_ >> 1;            // B region
    const int wbr = (wn_ & 1) * 64;      // row offset within B region

    // LDS regions: [buf][ab][region] x 8192 u16
    auto reg = [&](int buf, int ab, int half) -> u16* {
        return smem + (((buf << 1) | ab) * 2 + half) * 8192;
    };

    // staging source: per-thread hoisted base pointers (row&7 == r0&7 for both p)
    const int r0 = t >> 3;                               // 0..63
    const int csw = ((t & 7) * 8) ^ ((r0 & 7) * 8);      // inverse-swizzled col
    const u16* gA = A + (size_t)(m0 + r0) * K + csw;
    const u16* gB = Bt + (size_t)(n0 + r0) * K + csw;
    const size_t pK64 = (size_t)64 * K;
    const size_t hK128 = (size_t)128 * K;

    auto stA = [&](int u, int hf) {
        if (u >= NS) return;
        u16* d = reg(u & 1, 0, hf) + t * 8;
        const u16* s = gA + (size_t)(u * 64) + (hf ? hK128 : (size_t)0);
        gl_lds16(s, d);
        gl_lds16(s + pK64, d + 4096);
    };
    auto stB = [&](int u, int hf) {
        if (u >= NS) return;
        u16* d = reg(u & 1, 1, hf) + t * 8;
        const u16* s = gB + (size_t)(u * 64) + (hf ? hK128 : (size_t)0);
        gl_lds16(s, d);
        gl_lds16(s + pK64, d + 4096);
    };

    #pragma unroll
    for (int i = 0; i < 8; ++i)
        #pragma unroll
        for (int j = 0; j < 4; ++j) acc[i][j] = (f32x4){0.f, 0.f, 0.f, 0.f};

    // prologue: tile0 fully (issued first) + B(1); VM4 retires exactly tile0
    stB(0, 0); stB(0, 1); stA(0, 0); stA(0, 1);
    stB(1, 0); stB(1, 1);
    VM4();
    BARF();

    for (int s = 0; s < NS; ++s) {
        const u16* As = reg(s & 1, 0, wm_);
        const u16* Bs = reg(s & 1, 1, wbh);
        bf16x8 aF[4], bF[4][2];
        // ---- phase 0: read A-lo-k0 (4) + B-k0 (4); stage Alo(s+1) ----
        #pragma unroll
        for (int i = 0; i < 4; ++i) aF[i] = ldfrag(As, i * 16 + lm, 0, lq);
        #pragma unroll
        for (int j = 0; j < 4; ++j) bF[j][0] = ldfrag(Bs, wbr + j * 16 + lm, 0, lq);
        stA(s + 1, 0);
        BARF(); PRIO1();
        #pragma unroll
        for (int i = 0; i < 4; ++i)
            #pragma unroll
            for (int j = 0; j < 4; ++j)
                acc[i][j] = MFMA16(aF[i], bF[j][0], acc[i][j]);
        PRIO0(); LGKM0(); BARF();
        // ---- phase 1: read A-lo-k1 (4) + B-k1 (4); stage Ahi(s+1) ----
        #pragma unroll
        for (int i = 0; i < 4; ++i) aF[i] = ldfrag(As, i * 16 + lm, 32, lq);
        #pragma unroll
        for (int j = 0; j < 4; ++j) bF[j][1] = ldfrag(Bs, wbr + j * 16 + lm, 32, lq);
        stA(s + 1, 1);
        BARF(); PRIO1();
        #pragma unroll
        for (int i = 0; i < 4; ++i)
            #pragma unroll
            for (int j = 0; j < 4; ++j)
                acc[i][j] = MFMA16(aF[i], bF[j][1], acc[i][j]);
        PRIO0(); LGKM0(); BARF();
        // ---- phase 2: read A-hi-k0 (4); stage Blo(s+2) ----
        #pragma unroll
        for (int i = 0; i < 4; ++i) aF[i] = ldfrag(As, 64 + i * 16 + lm, 0, lq);
        stB(s + 2, 0);
        BARF(); PRIO1();
        #pragma unroll
        for (int i = 0; i < 4; ++i)
            #pragma unroll
            for (int j = 0; j < 4; ++j)
                acc[4 + i][j] = MFMA16(aF[i], bF[j][0], acc[4 + i][j]);
        PRIO0(); LGKM0(); BARF();
        // ---- phase 3: read A-hi-k1 (4); stage Bhi(s+2); vmcnt ----
        #pragma unroll
        for (int i = 0; i < 4; ++i) aF[i] = ldfrag(As, 64 + i * 16 + lm, 32, lq);
        stB(s + 2, 1);
        BARF(); PRIO1();
        #pragma unroll
        for (int i = 0; i < 4; ++i)
            #pragma unroll
            for (int j = 0; j < 4; ++j)
                acc[4 + i][j] = MFMA16(aF[i], bF[j][1], acc[4 + i][j]);
        PRIO0(); LGKM0();
        if (s >= NS - 2) { VM0(); } else { VM4(); }
        BARF();
    }
}

// ======== fused QKV: 256x256 tiles, 6 n-tiles (2 q | 2 k | 2 v) =============
__global__ __launch_bounds__(512) void qkv256_kernel(
    const u16* __restrict__ A,
    const u16* __restrict__ wqt, const u16* __restrict__ wkt, const u16* __restrict__ wvt,
    const float* __restrict__ bqp, const float* __restrict__ bkp, const float* __restrict__ bvp,
    u16* __restrict__ qb, u16* __restrict__ kb, u16* __restrict__ vb, float sclq)
{
    __shared__ u16 smem[65536];            // 128 KiB static
    int flat = blockIdx.x;                 // 768 blocks
    int xcd = flat & 7, slot = flat >> 3;
    int g = xcd * 96 + slot;               // bijective (768 % 8 == 0)
    int mt = g / 6, nt = g % 6;
    int mode = nt >> 1;                    // 0=q 1=k 2=v
    int m0 = mt * 256, nb0 = (nt & 1) * 256;
    const u16* Bt = (mode == 0) ? wqt : (mode == 1) ? wkt : wvt;
    const float* bias = (mode == 0) ? bqp : (mode == 1) ? bkp : bvp;
    u16* outp = (mode == 0) ? qb : (mode == 1) ? kb : vb;

    int t = threadIdx.x;
    f32x4 acc[8][4];
    gemm256_core(A, Bt, 512, m0, nb0, t, smem, acc);

    int wid = t >> 6, lane = t & 63, lm = lane & 15, lq = lane >> 4;
    int rowb = m0 + (wid >> 2) * 128;
    int colb = nb0 + (wid & 3) * 64;       // one 64-wide head per wave

    if (mode < 2) {   // q/k: RoPE + head layout [bc][h][s][d]
        float bv0 = bias[colb + 0 * 16 + lm];
        float bv1 = bias[colb + 1 * 16 + lm];
        float bv2 = bias[colb + 2 * 16 + lm];
        float bv3 = bias[colb + 3 * 16 + lm];
        float its = __expf((float)lm * -0.28782313662425572f);  // 10000^(-lm/32)
        float scl = (mode == 0) ? sclq : 1.f;
        #pragma unroll
        for (int i = 0; i < 8; ++i) {
            #pragma unroll
            for (int r = 0; r < 4; ++r) {
                int gm = rowb + i * 16 + lq * 4 + r;
                int s = gm & 511;
                float ang = (float)s * its;
                float sn = __sinf(ang), cs = __cosf(ang);
                float x1 = acc[i][0][r] + bv0;
                float x2 = acc[i][2][r] + bv2;
                float y0 = (x1 * cs - x2 * sn) * scl;
                float y2 = (x2 * cs + x1 * sn) * scl;
                float y1 = (acc[i][1][r] + bv1) * scl;
                float y3 = (acc[i][3][r] + bv3) * scl;
                size_t base = ((size_t)(gm >> 9)) * 262144 + (size_t)(colb >> 6) * 32768
                            + (size_t)s * 64 + lm;
                outp[base +  0] = f2bf(y0);
                outp[base + 16] = f2bf(y1);
                outp[base + 32] = f2bf(y2);
                outp[base + 48] = f2bf(y3);
            }
        }
    } else {          // v: transposed head layout [bc][h][d][s]
        #pragma unroll
        for (int i = 0; i < 8; ++i)
            #pragma unroll
            for (int j = 0; j < 4; ++j) {
                int gn = colb + j * 16 + lm;
                float bvv = bias[gn];
                #pragma unroll
                for (int r = 0; r < 4; ++r) {
                    int gm = rowb + i * 16 + lq * 4 + r;
                    float v = acc[i][j][r] + bvv;
                    size_t idx = ((size_t)(gm >> 9)) * 262144 + (size_t)(gn >> 6) * 32768
                               + (size_t)(gn & 63) * 512 + (gm & 511);
                    outp[idx] = f2bf(v);
                }
            }
    }
}

// -------- generic 256x256 8-phase GEMM --------
// MODE 3: out fp32 row-major, v=acc+bias+res ; MODE 4: out bf16, v=gelu(acc+bias)
template<int MODE>
__global__ __launch_bounds__(512) void gemm256_kernel(
    const u16* __restrict__ A, const u16* __restrict__ Bt,
    const float* __restrict__ bias, const float* __restrict__ res,
    void* __restrict__ outp, int M, int N, int K)
{
    __shared__ u16 smem[65536];            // 128 KiB static
    int flat = blockIdx.x;
    int nbt = N >> 8;
    int nwg = (M >> 8) * nbt;
    int xcd = flat & 7, slot = flat >> 3;
    int g = xcd * (nwg >> 3) + slot;       // grids are multiples of 8
    int mt = g / nbt, nt = g % nbt;
    int m0 = mt * 256, n0 = nt * 256;

    int t = threadIdx.x;
    f32x4 acc[8][4];
    gemm256_core(A, Bt, K, m0, n0, t, smem, acc);

    int wid = t >> 6, lane = t & 63, lm = lane & 15, lq = lane >> 4;
    int rowb = m0 + (wid >> 2) * 128, colb = n0 + (wid & 3) * 64;
    #pragma unroll
    for (int i = 0; i < 8; ++i)
        #pragma unroll
        for (int j = 0; j < 4; ++j) {
            int gn = colb + j * 16 + lm;
            float bv = bias[gn];
            #pragma unroll
            for (int r = 0; r < 4; ++r) {
                int gm = rowb + i * 16 + lq * 4 + r;
                float v = acc[i][j][r] + bv;
                if (MODE == 3) {
                    size_t idx = (size_t)gm * N + gn;
                    ((float*)outp)[idx] = v + res[idx];
                } else {
                    float gl = 0.5f * v * (1.f + erff(v * 0.70710678118654752f));
                    ((u16*)outp)[(size_t)gm * N + gn] = f2bf(gl);
                }
            }
        }
}

// ---------------- flash attention, transposed-S, 4 q-subtiles per stage ------
__global__ __launch_bounds__(256) void attn_kernel(
    const u16* __restrict__ q, const u16* __restrict__ k,
    const u16* __restrict__ vt, u16* __restrict__ o)
{
    int flat = blockIdx.y * gridDim.x + blockIdx.x;   // grid (2,512) = 1024 blocks
    int xcd = flat & 7, slot = flat >> 3;
    int nh = xcd * 64 + (slot >> 1);
    int qt = slot & 1;
    const u16* Qb = q + (size_t)nh * 32768 + (size_t)qt * 16384;
    const u16* Kb = k + (size_t)nh * 32768;
    const u16* Vb = vt + (size_t)nh * 32768;
    __shared__ u16 lK[64][72], lV[64][72];
    __shared__ u16 lP[4][16][72];
    int t = threadIdx.x, wid = t >> 6, lane = t & 63, lm = lane & 15, lq = lane >> 4;

    bf16x8 bq[4][2];
    #pragma unroll
    for (int sub = 0; sub < 4; ++sub) {
        const u16* qr = Qb + (size_t)(sub * 64 + wid * 16 + lm) * 64;
        bq[sub][0] = *(const bf16x8*)(qr + lq * 8);
        bq[sub][1] = *(const bf16x8*)(qr + 32 + lq * 8);
    }

    const f32x4 zero = {0.f, 0.f, 0.f, 0.f};
    f32x4 Oacc[4][4];
    float mo[4], l[4];
    #pragma unroll
    for (int s = 0; s < 4; ++s) {
        mo[s] = -INFINITY; l[s] = 0.f;
        #pragma unroll
        for (int d = 0; d < 4; ++d) Oacc[s][d] = zero;
    }

    for (int kt = 0; kt < 8; ++kt) {
        #pragma unroll
        for (int p = 0; p < 2; ++p) {
            int idx = p * 256 + t, row = idx >> 3, ch = (idx & 7) * 8;
            *(uint4*)&lK[row][ch] = *(const uint4*)(Kb + (size_t)(kt * 64 + row) * 64 + ch);
            *(uint4*)&lV[row][ch] = *(const uint4*)(Vb + (size_t)row * 512 + kt * 64 + ch);
        }
        __syncthreads();
        bf16x8 aK[4][2], aV[4][2];
        #pragma unroll
        for (int i = 0; i < 4; ++i) {
            aK[i][0] = *(const bf16x8*)&lK[i * 16 + lm][lq * 8];
            aK[i][1] = *(const bf16x8*)&lK[i * 16 + lm][32 + lq * 8];
            aV[i][0] = *(const bf16x8*)&lV[i * 16 + lm][lq * 8];
            aV[i][1] = *(const bf16x8*)&lV[i * 16 + lm][32 + lq * 8];
        }
        #pragma unroll
        for (int sub = 0; sub < 4; ++sub) {
            f32x4 sc[4];
            #pragma unroll
            for (int i = 0; i < 4; ++i) {
                f32x4 z = MFMA16(aK[i][0], bq[sub][0], zero);
                sc[i] = MFMA16(aK[i][1], bq[sub][1], z);
            }
            float mx = sc[0][0];
            #pragma unroll
            for (int i = 0; i < 4; ++i)
                #pragma unroll
                for (int r = 0; r < 4; ++r) mx = fmaxf(mx, sc[i][r]);
            mx = fmaxf(mx, __shfl_xor(mx, 16, 64));
            mx = fmaxf(mx, __shfl_xor(mx, 32, 64));
            float mn = fmaxf(mo[sub], mx);
            float al = fexp2(mo[sub] - mn);
            float pv[4][4], sum = 0.f;
            #pragma unroll
            for (int i = 0; i < 4; ++i)
                #pragma unroll
                for (int r = 0; r < 4; ++r) { pv[i][r] = fexp2(sc[i][r] - mn); sum += pv[i][r]; }
            sum += __shfl_xor(sum, 16, 64);
            sum += __shfl_xor(sum, 32, 64);
            l[sub] = l[sub] * al + sum;
            mo[sub] = mn;
            #pragma unroll
            for (int dn = 0; dn < 4; ++dn) Oacc[sub][dn] *= al;
            #pragma unroll
            for (int i = 0; i < 4; ++i) {
                uint2 w2;
                w2.x = pack_bf16(pv[i][0], pv[i][1]);
                w2.y = pack_bf16(pv[i][2], pv[i][3]);
                *(uint2*)&lP[wid][lm][i * 16 + lq * 4] = w2;
            }
            bf16x8 bp0 = *(const bf16x8*)&lP[wid][lm][lq * 8];
            bf16x8 bp1 = *(const bf16x8*)&lP[wid][lm][32 + lq * 8];
            #pragma unroll
            for (int dn = 0; dn < 4; ++dn) {
                Oacc[sub][dn] = MFMA16(aV[dn][0], bp0, Oacc[sub][dn]);
                Oacc[sub][dn] = MFMA16(aV[dn][1], bp1, Oacc[sub][dn]);
            }
        }
        __syncthreads();
    }
    int bc = nh >> 3, h = nh & 7;
    #pragma unroll
    for (int sub = 0; sub < 4; ++sub) {
        float inv = 1.f / l[sub];
        size_t orow = ((size_t)(bc * 512 + qt * 256 + sub * 64 + wid * 16 + lm)) * 512 + h * 64;
        #pragma unroll
        for (int dn = 0; dn < 4; ++dn) {
            uint2 w2;
            w2.x = pack_bf16(Oacc[sub][dn][0] * inv, Oacc[sub][dn][1] * inv);
            w2.y = pack_bf16(Oacc[sub][dn][2] * inv, Oacc[sub][dn][3] * inv);
            *(uint2*)(o + orow + dn * 16 + lq * 4) = w2;
        }
    }
}

extern "C" void kernel_launch(void* const* d_in, const int* in_sizes, int n_in,
                              void* d_out, int out_size, void* d_ws, size_t ws_size,
                              hipStream_t stream) {
    const float* x    = (const float*)d_in[0];
    const float* Wq   = (const float*)d_in[1];
    const float* bq   = (const float*)d_in[2];
    const float* Wk   = (const float*)d_in[3];
    const float* bk   = (const float*)d_in[4];
    const float* Wv   = (const float*)d_in[5];
    const float* bv   = (const float*)d_in[6];
    const float* Wo   = (const float*)d_in[7];
    const float* bo   = (const float*)d_in[8];
    const float* ln1g = (const float*)d_in[9];
    const float* ln1b = (const float*)d_in[10];
    const float* ln3g = (const float*)d_in[11];
    const float* ln3b = (const float*)d_in[12];
    const float* W1   = (const float*)d_in[13];
    const float* b1   = (const float*)d_in[14];
    const float* W2   = (const float*)d_in[15];
    const float* b2   = (const float*)d_in[16];

    char* ws = (char*)d_ws;
    u16*  hn  = (u16*)(ws + 0ull);            // 33,554,432  (also hn2)
    u16*  qb  = (u16*)(ws + 33554432ull);     // 33,554,432
    u16*  kb  = (u16*)(ws + 67108864ull);     // 33,554,432
    u16*  vb  = (u16*)(ws + 100663296ull);    // 33,554,432
    u16*  ob  = (u16*)(ws + 134217728ull);    // 33,554,432
    u16*  ffa = (u16*)(ws + 33554432ull);     // 134,217,728 (after o consumed)
    float* h1 = (float*)(ws + 167772160ull);  // 67,108,864
    u16*  wqt = (u16*)(ws + 234881024ull);
    u16*  wkt = (u16*)(ws + 235405312ull);
    u16*  wvt = (u16*)(ws + 235929600ull);
    u16*  wot = (u16*)(ws + 236453888ull);
    u16*  w1t = (u16*)(ws + 236978176ull);    // 2,097,152
    u16*  w2t = (u16*)(ws + 239075328ull);    // 2,097,152

    dim3 blk(256);
    transpose_cvt_all<<<768, blk, 0, stream>>>(Wq, Wk, Wv, Wo, W1, W2,
                                               wqt, wkt, wvt, wot, w1t, w2t);

    ln_kernel<<<32768, blk, 0, stream>>>(x, hn, ln1g, ln1b);

    // q scale folds HD^-0.5 and log2(e) (softmax computed base-2)
    qkv256_kernel<<<768, dim3(512), 0, stream>>>(hn, wqt, wkt, wvt, bq, bk, bv,
                                                 qb, kb, vb,
                                                 0.125f * 1.4426950408889634f);

    attn_kernel<<<dim3(2, 512), blk, 0, stream>>>(qb, kb, vb, ob);

    gemm256_kernel<3><<<256, dim3(512), 0, stream>>>(ob, wot, bo, x, h1,
                                                     32768, 512, 512);

    ln_kernel<<<32768, blk, 0, stream>>>(h1, hn, ln3g, ln3b);

    gemm256_kernel<4><<<1024, dim3(512), 0, stream>>>(hn, w1t, b1, nullptr, ffa,
                                                      32768, 2048, 512);
    gemm256_kernel<3><<<256, dim3(512), 0, stream>>>(ffa, w2t, b2, h1,
                                                     (float*)d_out, 32768, 512, 2048);
}

// Round 6
// 583.303 us; speedup vs baseline: 1.0324x; 1.0324x over previous
//
#include <hip/hip_runtime.h>
#include <math.h>

typedef unsigned short u16;
typedef __attribute__((ext_vector_type(8))) short bf16x8;
typedef __attribute__((ext_vector_type(4))) float f32x4;

#define MFMA16(a, b, c) __builtin_amdgcn_mfma_f32_16x16x32_bf16((a), (b), (c), 0, 0, 0)

__device__ __forceinline__ u16 f2bf(float f) {
    union { float f; unsigned u; } v; v.f = f;
    unsigned u = v.u;
    unsigned r = (u + 0x7FFFu + ((u >> 16) & 1u)) >> 16;
    return (u16)r;
}

// pack two floats -> (bf16(hi)<<16)|bf16(lo), round-half-up, one v_perm_b32
__device__ __forceinline__ unsigned pack_bf16(float lo, float hi) {
    union { float f; unsigned u; } a, b; a.f = lo; b.f = hi;
    return __builtin_amdgcn_perm(b.u + 0x8000u, a.u + 0x8000u, 0x07060302u);
}

__device__ __forceinline__ float fexp2(float x) {
#if __has_builtin(__builtin_amdgcn_exp2f)
    return __builtin_amdgcn_exp2f(x);
#else
    return __expf(x * 0.6931471805599453f);
#endif
}

__device__ __forceinline__ float frcp(float x) {
#if __has_builtin(__builtin_amdgcn_rcpf)
    return __builtin_amdgcn_rcpf(x);
#else
    return 1.0f / x;
#endif
}

// tanh-form GELU via exp2+rcp: ~7 VALU ops vs ~30+ for erff.
// gelu(x) = x * sigmoid(2u), u = sqrt(2/pi)*(x + 0.044715 x^3)
__device__ __forceinline__ float fgelu(float v) {
    float x2 = v * v;
    float u = v * (0.7978845608028654f + 0.035677408136300125f * x2);
    return v * frcp(1.0f + fexp2(-2.8853900817779268f * u));
}

// async 16B/lane global->LDS DMA. LDS dest must be lane-linear (base + lane*16).
__device__ __forceinline__ void gl_lds16(const u16* g, u16* l) {
    __builtin_amdgcn_global_load_lds(
        (const __attribute__((address_space(1))) unsigned*)g,
        (__attribute__((address_space(3))) unsigned*)l, 16, 0, 0);
}

// -------- all-weights transpose + fp32->bf16 convert, single dispatch --------
__global__ __launch_bounds__(256) void transpose_cvt_all(
    const float* __restrict__ Wq, const float* __restrict__ Wk,
    const float* __restrict__ Wv, const float* __restrict__ Wo,
    const float* __restrict__ W1, const float* __restrict__ W2,
    u16* __restrict__ wqt, u16* __restrict__ wkt, u16* __restrict__ wvt,
    u16* __restrict__ wot, u16* __restrict__ w1t, u16* __restrict__ w2t)
{
    __shared__ float tile[64][65];
    int fb = blockIdx.x;
    const float* src; u16* dst; int K, N, bx, by;
    if (fb < 256) {
        int w = fb >> 6, b = fb & 63;
        src = (w == 0) ? Wq : (w == 1) ? Wk : (w == 2) ? Wv : Wo;
        dst = (w == 0) ? wqt : (w == 1) ? wkt : (w == 2) ? wvt : wot;
        K = 512; N = 512; bx = b & 7; by = b >> 3;
    } else if (fb < 512) {
        int b = fb - 256; src = W1; dst = w1t; K = 512; N = 2048; bx = b & 31; by = b >> 5;
    } else {
        int b = fb - 512; src = W2; dst = w2t; K = 2048; N = 512; bx = b & 7; by = b >> 3;
    }
    int n0 = bx * 64, k0 = by * 64;
    int tx = threadIdx.x & 63, ty = threadIdx.x >> 6;
    #pragma unroll
    for (int i = ty; i < 64; i += 4)
        tile[i][tx] = src[(size_t)(k0 + i) * N + n0 + tx];
    __syncthreads();
    #pragma unroll
    for (int i = ty; i < 64; i += 4)
        dst[(size_t)(n0 + i) * K + k0 + tx] = f2bf(tile[tx][i]);
}

// ---------------- layernorm: fp32 in -> bf16 out, rows of 512 ----------------
__global__ __launch_bounds__(256) void ln_kernel(const float* __restrict__ in,
                                                 u16* __restrict__ out,
                                                 const float* __restrict__ g,
                                                 const float* __restrict__ b) {
    int row = blockIdx.x;
    const float* rp = in + (size_t)row * 512;
    int t = threadIdx.x;
    float2 v = *(const float2*)(rp + t * 2);
    float s = v.x + v.y;
    float sq = v.x * v.x + v.y * v.y;
    #pragma unroll
    for (int off = 32; off > 0; off >>= 1) {
        s  += __shfl_down(s, off, 64);
        sq += __shfl_down(sq, off, 64);
    }
    __shared__ float red[8];
    __shared__ float stat[2];
    int wid = t >> 6;
    if ((t & 63) == 0) { red[wid] = s; red[wid + 4] = sq; }
    __syncthreads();
    if (t == 0) {
        float S = red[0] + red[1] + red[2] + red[3];
        float Q = red[4] + red[5] + red[6] + red[7];
        float mu = S * (1.0f / 512.0f);
        float var = Q * (1.0f / 512.0f) - mu * mu;
        stat[0] = mu;
        stat[1] = rsqrtf(var + 1e-5f);
    }
    __syncthreads();
    float mu = stat[0], inv = stat[1];
    int c = t * 2;
    float2 gv = *(const float2*)(g + c);
    float2 bv = *(const float2*)(b + c);
    ushort2 ov;
    ov.x = f2bf((v.x - mu) * inv * gv.x + bv.x);
    ov.y = f2bf((v.y - mu) * inv * gv.y + bv.y);
    *(ushort2*)(out + (size_t)row * 512 + c) = ov;
}

// ================== 256x256 8-phase MFMA GEMM machinery ======================
// BM=BN=256, BK=64, 512 threads = 8 waves (2M x 4N), per-wave out 128x64.
// LDS 128 KiB STATIC: [buf2][A/B][region2][128x64 bf16]. XOR-swizzle
// byte^=(row&7)<<4 via inverse-swizzled GLOBAL source + swizzled ds_read.
// REGION SEMANTICS: stA(u,hf) writes the WHOLE 128-row region hf, and the
// wm_=hf waves read that region in ALL FOUR phases.  So A regions may only
// be staged 1-step-ahead, at ph0 (both halves: readers of the opposite buf
// finished at the previous step's end barrier).  B regions are fully read
// by end of ph1 (k0 at ph0, k1 at ph1), so B stages 2-steps-ahead at
// ph2/ph3.  Reads balanced 8/8/4/4.  lgkmcnt(0) AFTER each MFMA cluster
// (before barrier #2): MFMAs use compiler-counted waits, the pre-barrier
// drain keeps the cross-wave WAR guarantee.
// vmcnt(4) at step end retires tile s+1 (FIFO: B(s+1) then A(s+1), leaves
// B(s+2)); vmcnt(0) on the last two steps.

#define FENCE() asm volatile("" ::: "memory")
#define BARF()  do { FENCE(); __builtin_amdgcn_s_barrier(); FENCE(); } while (0)
#define LGKM0() asm volatile("s_waitcnt lgkmcnt(0)" ::: "memory")
#define VM4()   asm volatile("s_waitcnt vmcnt(4)" ::: "memory")
#define VM0()   asm volatile("s_waitcnt vmcnt(0)" ::: "memory")
#define PRIO1() __builtin_amdgcn_s_setprio(1)
#define PRIO0() __builtin_amdgcn_s_setprio(0)

// swizzled fragment read: region is [128 rows][64 bf16], 16B-aligned groups
__device__ __forceinline__ bf16x8 ldfrag(const u16* __restrict__ base, int R, int ko, int lq) {
    int o = (ko + lq * 8) ^ ((R & 7) * 8);
    return *(const bf16x8*)(base + R * 64 + o);
}

__device__ __forceinline__ void gemm256_core(
    const u16* __restrict__ A, const u16* __restrict__ Bt, int K,
    int m0, int n0, int t, u16* __restrict__ smem, f32x4 (&acc)[8][4])
{
    const int NS = K >> 6;
    const int wid = t >> 6, lane = t & 63;
    const int lm = lane & 15, lq = lane >> 4;
    const int wm_ = wid >> 2;            // warp_m: A region
    const int wn_ = wid & 3;             // warp_n
    const int wbh = wn_ >> 1;            // B region
    const int wbr = (wn_ & 1) * 64;      // row offset within B region

    // LDS regions: [buf][ab][region] x 8192 u16
    auto reg = [&](int buf, int ab, int half) -> u16* {
        return smem + (((buf << 1) | ab) * 2 + half) * 8192;
    };

    // staging source: per-thread hoisted base pointers (row&7 == r0&7 for both p)
    const int r0 = t >> 3;                               // 0..63
    const int csw = ((t & 7) * 8) ^ ((r0 & 7) * 8);      // inverse-swizzled col
    const u16* gA = A + (size_t)(m0 + r0) * K + csw;
    const u16* gB = Bt + (size_t)(n0 + r0) * K + csw;
    const size_t pK64 = (size_t)64 * K;
    const size_t hK128 = (size_t)128 * K;

    auto stA = [&](int u, int hf) {
        if (u >= NS) return;
        u16* d = reg(u & 1, 0, hf) + t * 8;
        const u16* s = gA + (size_t)(u * 64) + (hf ? hK128 : (size_t)0);
        gl_lds16(s, d);
        gl_lds16(s + pK64, d + 4096);
    };
    auto stB = [&](int u, int hf) {
        if (u >= NS) return;
        u16* d = reg(u & 1, 1, hf) + t * 8;
        const u16* s = gB + (size_t)(u * 64) + (hf ? hK128 : (size_t)0);
        gl_lds16(s, d);
        gl_lds16(s + pK64, d + 4096);
    };

    #pragma unroll
    for (int i = 0; i < 8; ++i)
        #pragma unroll
        for (int j = 0; j < 4; ++j) acc[i][j] = (f32x4){0.f, 0.f, 0.f, 0.f};

    // prologue: tile0 fully (issued first) + B(1); VM4 retires exactly tile0
    stB(0, 0); stB(0, 1); stA(0, 0); stA(0, 1);
    stB(1, 0); stB(1, 1);
    VM4();
    BARF();

    for (int s = 0; s < NS; ++s) {
        const u16* As = reg(s & 1, 0, wm_);
        const u16* Bs = reg(s & 1, 1, wbh);
        bf16x8 aF[4], bF[4][2];
        // ---- phase 0: read A-lo-k0 (4) + B-k0 (4); stage Alo+Ahi(s+1) ----
        #pragma unroll
        for (int i = 0; i < 4; ++i) aF[i] = ldfrag(As, i * 16 + lm, 0, lq);
        #pragma unroll
        for (int j = 0; j < 4; ++j) bF[j][0] = ldfrag(Bs, wbr + j * 16 + lm, 0, lq);
        stA(s + 1, 0);
        stA(s + 1, 1);
        BARF(); PRIO1();
        #pragma unroll
        for (int i = 0; i < 4; ++i)
            #pragma unroll
            for (int j = 0; j < 4; ++j)
                acc[i][j] = MFMA16(aF[i], bF[j][0], acc[i][j]);
        PRIO0(); LGKM0(); BARF();
        // ---- phase 1: read A-lo-k1 (4) + B-k1 (4); no stage ----
        #pragma unroll
        for (int i = 0; i < 4; ++i) aF[i] = ldfrag(As, i * 16 + lm, 32, lq);
        #pragma unroll
        for (int j = 0; j < 4; ++j) bF[j][1] = ldfrag(Bs, wbr + j * 16 + lm, 32, lq);
        BARF(); PRIO1();
        #pragma unroll
        for (int i = 0; i < 4; ++i)
            #pragma unroll
            for (int j = 0; j < 4; ++j)
                acc[i][j] = MFMA16(aF[i], bF[j][1], acc[i][j]);
        PRIO0(); LGKM0(); BARF();
        // ---- phase 2: read A-hi-k0 (4); stage Blo(s+2) ----
        #pragma unroll
        for (int i = 0; i < 4; ++i) aF[i] = ldfrag(As, 64 + i * 16 + lm, 0, lq);
        stB(s + 2, 0);
        BARF(); PRIO1();
        #pragma unroll
        for (int i = 0; i < 4; ++i)
            #pragma unroll
            for (int j = 0; j < 4; ++j)
                acc[4 + i][j] = MFMA16(aF[i], bF[j][0], acc[4 + i][j]);
        PRIO0(); LGKM0(); BARF();
        // ---- phase 3: read A-hi-k1 (4); stage Bhi(s+2); vmcnt ----
        #pragma unroll
        for (int i = 0; i < 4; ++i) aF[i] = ldfrag(As, 64 + i * 16 + lm, 32, lq);
        stB(s + 2, 1);
        BARF(); PRIO1();
        #pragma unroll
        for (int i = 0; i < 4; ++i)
            #pragma unroll
            for (int j = 0; j < 4; ++j)
                acc[4 + i][j] = MFMA16(aF[i], bF[j][1], acc[4 + i][j]);
        PRIO0(); LGKM0();
        if (s >= NS - 2) { VM0(); } else { VM4(); }
        BARF();
    }
}

// ======== fused QKV: 256x256 tiles, 6 n-tiles (2 q | 2 k | 2 v) =============
__global__ __launch_bounds__(512) void qkv256_kernel(
    const u16* __restrict__ A,
    const u16* __restrict__ wqt, const u16* __restrict__ wkt, const u16* __restrict__ wvt,
    const float* __restrict__ bqp, const float* __restrict__ bkp, const float* __restrict__ bvp,
    u16* __restrict__ qb, u16* __restrict__ kb, u16* __restrict__ vb, float sclq)
{
    __shared__ u16 smem[65536];            // 128 KiB static
    int flat = blockIdx.x;                 // 768 blocks
    int xcd = flat & 7, slot = flat >> 3;
    int g = xcd * 96 + slot;               // bijective (768 % 8 == 0)
    int mt = g / 6, nt = g % 6;
    int mode = nt >> 1;                    // 0=q 1=k 2=v
    int m0 = mt * 256, nb0 = (nt & 1) * 256;
    const u16* Bt = (mode == 0) ? wqt : (mode == 1) ? wkt : wvt;
    const float* bias = (mode == 0) ? bqp : (mode == 1) ? bkp : bvp;
    u16* outp = (mode == 0) ? qb : (mode == 1) ? kb : vb;

    int t = threadIdx.x;
    f32x4 acc[8][4];
    gemm256_core(A, Bt, 512, m0, nb0, t, smem, acc);

    int wid = t >> 6, lane = t & 63, lm = lane & 15, lq = lane >> 4;
    int rowb = m0 + (wid >> 2) * 128;
    int colb = nb0 + (wid & 3) * 64;       // one 64-wide head per wave

    if (mode < 2) {   // q/k: RoPE + head layout [bc][h][s][d]
        float bv0 = bias[colb + 0 * 16 + lm];
        float bv1 = bias[colb + 1 * 16 + lm];
        float bv2 = bias[colb + 2 * 16 + lm];
        float bv3 = bias[colb + 3 * 16 + lm];
        float its = __expf((float)lm * -0.28782313662425572f);  // 10000^(-lm/32)
        float scl = (mode == 0) ? sclq : 1.f;
        #pragma unroll
        for (int i = 0; i < 8; ++i) {
            #pragma unroll
            for (int r = 0; r < 4; ++r) {
                int gm = rowb + i * 16 + lq * 4 + r;
                int s = gm & 511;
                float ang = (float)s * its;
                float sn = __sinf(ang), cs = __cosf(ang);
                float x1 = acc[i][0][r] + bv0;
                float x2 = acc[i][2][r] + bv2;
                float y0 = (x1 * cs - x2 * sn) * scl;
                float y2 = (x2 * cs + x1 * sn) * scl;
                float y1 = (acc[i][1][r] + bv1) * scl;
                float y3 = (acc[i][3][r] + bv3) * scl;
                size_t base = ((size_t)(gm >> 9)) * 262144 + (size_t)(colb >> 6) * 32768
                            + (size_t)s * 64 + lm;
                outp[base +  0] = f2bf(y0);
                outp[base + 16] = f2bf(y1);
                outp[base + 32] = f2bf(y2);
                outp[base + 48] = f2bf(y3);
            }
        }
    } else {          // v: transposed head layout [bc][h][d][s]
        #pragma unroll
        for (int i = 0; i < 8; ++i)
            #pragma unroll
            for (int j = 0; j < 4; ++j) {
                int gn = colb + j * 16 + lm;
                float bvv = bias[gn];
                #pragma unroll
                for (int r = 0; r < 4; ++r) {
                    int gm = rowb + i * 16 + lq * 4 + r;
                    float v = acc[i][j][r] + bvv;
                    size_t idx = ((size_t)(gm >> 9)) * 262144 + (size_t)(gn >> 6) * 32768
                               + (size_t)(gn & 63) * 512 + (gm & 511);
                    outp[idx] = f2bf(v);
                }
            }
    }
}

// -------- generic 256x256 8-phase GEMM --------
// MODE 3: out fp32 row-major, v=acc+bias+res ; MODE 4: out bf16, v=gelu(acc+bias)
template<int MODE>
__global__ __launch_bounds__(512) void gemm256_kernel(
    const u16* __restrict__ A, const u16* __restrict__ Bt,
    const float* __restrict__ bias, const float* __restrict__ res,
    void* __restrict__ outp, int M, int N, int K)
{
    __shared__ u16 smem[65536];            // 128 KiB static
    int flat = blockIdx.x;
    int nbt = N >> 8;
    int nwg = (M >> 8) * nbt;
    int xcd = flat & 7, slot = flat >> 3;
    int g = xcd * (nwg >> 3) + slot;       // grids are multiples of 8
    int mt = g / nbt, nt = g % nbt;
    int m0 = mt * 256, n0 = nt * 256;

    int t = threadIdx.x;
    f32x4 acc[8][4];
    gemm256_core(A, Bt, K, m0, n0, t, smem, acc);

    int wid = t >> 6, lane = t & 63, lm = lane & 15, lq = lane >> 4;
    int rowb = m0 + (wid >> 2) * 128, colb = n0 + (wid & 3) * 64;
    #pragma unroll
    for (int i = 0; i < 8; ++i)
        #pragma unroll
        for (int j = 0; j < 4; ++j) {
            int gn = colb + j * 16 + lm;
            float bv = bias[gn];
            #pragma unroll
            for (int r = 0; r < 4; ++r) {
                int gm = rowb + i * 16 + lq * 4 + r;
                float v = acc[i][j][r] + bv;
                if (MODE == 3) {
                    size_t idx = (size_t)gm * N + gn;
                    ((float*)outp)[idx] = v + res[idx];
                } else {
                    ((u16*)outp)[(size_t)gm * N + gn] = f2bf(fgelu(v));
                }
            }
        }
}

// ---------------- flash attention, transposed-S, 4 q-subtiles per stage ------
__global__ __launch_bounds__(256) void attn_kernel(
    const u16* __restrict__ q, const u16* __restrict__ k,
    const u16* __restrict__ vt, u16* __restrict__ o)
{
    int flat = blockIdx.y * gridDim.x + blockIdx.x;   // grid (2,512) = 1024 blocks
    int xcd = flat & 7, slot = flat >> 3;
    int nh = xcd * 64 + (slot >> 1);
    int qt = slot & 1;
    const u16* Qb = q + (size_t)nh * 32768 + (size_t)qt * 16384;
    const u16* Kb = k + (size_t)nh * 32768;
    const u16* Vb = vt + (size_t)nh * 32768;
    __shared__ u16 lK[64][72], lV[64][72];
    __shared__ u16 lP[4][16][72];
    int t = threadIdx.x, wid = t >> 6, lane = t & 63, lm = lane & 15, lq = lane >> 4;

    bf16x8 bq[4][2];
    #pragma unroll
    for (int sub = 0; sub < 4; ++sub) {
        const u16* qr = Qb + (size_t)(sub * 64 + wid * 16 + lm) * 64;
        bq[sub][0] = *(const bf16x8*)(qr + lq * 8);
        bq[sub][1] = *(const bf16x8*)(qr + 32 + lq * 8);
    }

    const f32x4 zero = {0.f, 0.f, 0.f, 0.f};
    f32x4 Oacc[4][4];
    float mo[4], l[4];
    #pragma unroll
    for (int s = 0; s < 4; ++s) {
        mo[s] = -INFINITY; l[s] = 0.f;
        #pragma unroll
        for (int d = 0; d < 4; ++d) Oacc[s][d] = zero;
    }

    for (int kt = 0; kt < 8; ++kt) {
        #pragma unroll
        for (int p = 0; p < 2; ++p) {
            int idx = p * 256 + t, row = idx >> 3, ch = (idx & 7) * 8;
            *(uint4*)&lK[row][ch] = *(const uint4*)(Kb + (size_t)(kt * 64 + row) * 64 + ch);
            *(uint4*)&lV[row][ch] = *(const uint4*)(Vb + (size_t)row * 512 + kt * 64 + ch);
        }
        __syncthreads();
        bf16x8 aK[4][2], aV[4][2];
        #pragma unroll
        for (int i = 0; i < 4; ++i) {
            aK[i][0] = *(const bf16x8*)&lK[i * 16 + lm][lq * 8];
            aK[i][1] = *(const bf16x8*)&lK[i * 16 + lm][32 + lq * 8];
            aV[i][0] = *(const bf16x8*)&lV[i * 16 + lm][lq * 8];
            aV[i][1] = *(const bf16x8*)&lV[i * 16 + lm][32 + lq * 8];
        }
        #pragma unroll
        for (int sub = 0; sub < 4; ++sub) {
            f32x4 sc[4];
            #pragma unroll
            for (int i = 0; i < 4; ++i) {
                f32x4 z = MFMA16(aK[i][0], bq[sub][0], zero);
                sc[i] = MFMA16(aK[i][1], bq[sub][1], z);
            }
            float mx = sc[0][0];
            #pragma unroll
            for (int i = 0; i < 4; ++i)
                #pragma unroll
                for (int r = 0; r < 4; ++r) mx = fmaxf(mx, sc[i][r]);
            mx = fmaxf(mx, __shfl_xor(mx, 16, 64));
            mx = fmaxf(mx, __shfl_xor(mx, 32, 64));
            float mn = fmaxf(mo[sub], mx);
            float al = fexp2(mo[sub] - mn);
            float pv[4][4], sum = 0.f;
            #pragma unroll
            for (int i = 0; i < 4; ++i)
                #pragma unroll
                for (int r = 0; r < 4; ++r) { pv[i][r] = fexp2(sc[i][r] - mn); sum += pv[i][r]; }
            sum += __shfl_xor(sum, 16, 64);
            sum += __shfl_xor(sum, 32, 64);
            l[sub] = l[sub] * al + sum;
            mo[sub] = mn;
            #pragma unroll
            for (int dn = 0; dn < 4; ++dn) Oacc[sub][dn] *= al;
            #pragma unroll
            for (int i = 0; i < 4; ++i) {
                uint2 w2;
                w2.x = pack_bf16(pv[i][0], pv[i][1]);
                w2.y = pack_bf16(pv[i][2], pv[i][3]);
                *(uint2*)&lP[wid][lm][i * 16 + lq * 4] = w2;
            }
            bf16x8 bp0 = *(const bf16x8*)&lP[wid][lm][lq * 8];
            bf16x8 bp1 = *(const bf16x8*)&lP[wid][lm][32 + lq * 8];
            #pragma unroll
            for (int dn = 0; dn < 4; ++dn) {
                Oacc[sub][dn] = MFMA16(aV[dn][0], bp0, Oacc[sub][dn]);
                Oacc[sub][dn] = MFMA16(aV[dn][1], bp1, Oacc[sub][dn]);
            }
        }
        __syncthreads();
    }
    int bc = nh >> 3, h = nh & 7;
    #pragma unroll
    for (int sub = 0; sub < 4; ++sub) {
        float inv = 1.f / l[sub];
        size_t orow = ((size_t)(bc * 512 + qt * 256 + sub * 64 + wid * 16 + lm)) * 512 + h * 64;
        #pragma unroll
        for (int dn = 0; dn < 4; ++dn) {
            uint2 w2;
            w2.x = pack_bf16(Oacc[sub][dn][0] * inv, Oacc[sub][dn][1] * inv);
            w2.y = pack_bf16(Oacc[sub][dn][2] * inv, Oacc[sub][dn][3] * inv);
            *(uint2*)(o + orow + dn * 16 + lq * 4) = w2;
        }
    }
}

extern "C" void kernel_launch(void* const* d_in, const int* in_sizes, int n_in,
                              void* d_out, int out_size, void* d_ws, size_t ws_size,
                              hipStream_t stream) {
    const float* x    = (const float*)d_in[0];
    const float* Wq   = (const float*)d_in[1];
    const float* bq   = (const float*)d_in[2];
    const float* Wk   = (const float*)d_in[3];
    const float* bk   = (const float*)d_in[4];
    const float* Wv   = (const float*)d_in[5];
    const float* bv   = (const float*)d_in[6];
    const float* Wo   = (const float*)d_in[7];
    const float* bo   = (const float*)d_in[8];
    const float* ln1g = (const float*)d_in[9];
    const float* ln1b = (const float*)d_in[10];
    const float* ln3g = (const float*)d_in[11];
    const float* ln3b = (const float*)d_in[12];
    const float* W1   = (const float*)d_in[13];
    const float* b1   = (const float*)d_in[14];
    const float* W2   = (const float*)d_in[15];
    const float* b2   = (const float*)d_in[16];

    char* ws = (char*)d_ws;
    u16*  hn  = (u16*)(ws + 0ull);            // 33,554,432  (also hn2)
    u16*  qb  = (u16*)(ws + 33554432ull);     // 33,554,432
    u16*  kb  = (u16*)(ws + 67108864ull);     // 33,554,432
    u16*  vb  = (u16*)(ws + 100663296ull);    // 33,554,432
    u16*  ob  = (u16*)(ws + 134217728ull);    // 33,554,432
    u16*  ffa = (u16*)(ws + 33554432ull);     // 134,217,728 (after o consumed)
    float* h1 = (float*)(ws + 167772160ull);  // 67,108,864
    u16*  wqt = (u16*)(ws + 234881024ull);
    u16*  wkt = (u16*)(ws + 235405312ull);
    u16*  wvt = (u16*)(ws + 235929600ull);
    u16*  wot = (u16*)(ws + 236453888ull);
    u16*  w1t = (u16*)(ws + 236978176ull);    // 2,097,152
    u16*  w2t = (u16*)(ws + 239075328ull);    // 2,097,152

    dim3 blk(256);
    transpose_cvt_all<<<768, blk, 0, stream>>>(Wq, Wk, Wv, Wo, W1, W2,
                                               wqt, wkt, wvt, wot, w1t, w2t);

    ln_kernel<<<32768, blk, 0, stream>>>(x, hn, ln1g, ln1b);

    // q scale folds HD^-0.5 and log2(e) (softmax computed base-2)
    qkv256_kernel<<<768, dim3(512), 0, stream>>>(hn, wqt, wkt, wvt, bq, bk, bv,
                                                 qb, kb, vb,
                                                 0.125f * 1.4426950408889634f);

    attn_kernel<<<dim3(2, 512), blk, 0, stream>>>(qb, kb, vb, ob);

    gemm256_kernel<3><<<256, dim3(512), 0, stream>>>(ob, wot, bo, x, h1,
                                                     32768, 512, 512);

    ln_kernel<<<32768, blk, 0, stream>>>(h1, hn, ln3g, ln3b);

    gemm256_kernel<4><<<1024, dim3(512), 0, stream>>>(hn, w1t, b1, nullptr, ffa,
                                                      32768, 2048, 512);
    gemm256_kernel<3><<<256, dim3(512), 0, stream>>>(ffa, w2t, b2, h1,
                                                     (float*)d_out, 32768, 512, 2048);
}

// Round 7
// 548.889 us; speedup vs baseline: 1.0971x; 1.0627x over previous
//
#include <hip/hip_runtime.h>
#include <math.h>

typedef unsigned short u16;
typedef __attribute__((ext_vector_type(8))) short bf16x8;
typedef __attribute__((ext_vector_type(4))) float f32x4;

#define MFMA16(a, b, c) __builtin_amdgcn_mfma_f32_16x16x32_bf16((a), (b), (c), 0, 0, 0)

__device__ __forceinline__ u16 f2bf(float f) {
    union { float f; unsigned u; } v; v.f = f;
    unsigned u = v.u;
    unsigned r = (u + 0x7FFFu + ((u >> 16) & 1u)) >> 16;
    return (u16)r;
}

// pack two floats -> (bf16(hi)<<16)|bf16(lo), round-half-up, one v_perm_b32
__device__ __forceinline__ unsigned pack_bf16(float lo, float hi) {
    union { float f; unsigned u; } a, b; a.f = lo; b.f = hi;
    return __builtin_amdgcn_perm(b.u + 0x8000u, a.u + 0x8000u, 0x07060302u);
}

__device__ __forceinline__ float fexp2(float x) {
#if __has_builtin(__builtin_amdgcn_exp2f)
    return __builtin_amdgcn_exp2f(x);
#else
    return __expf(x * 0.6931471805599453f);
#endif
}

__device__ __forceinline__ float frcp(float x) {
#if __has_builtin(__builtin_amdgcn_rcpf)
    return __builtin_amdgcn_rcpf(x);
#else
    return 1.0f / x;
#endif
}

// tanh-form GELU via exp2+rcp: ~7 VALU ops vs ~30+ for erff.
__device__ __forceinline__ float fgelu(float v) {
    float x2 = v * v;
    float u = v * (0.7978845608028654f + 0.035677408136300125f * x2);
    return v * frcp(1.0f + fexp2(-2.8853900817779268f * u));
}

// async 16B/lane global->LDS DMA. LDS dest must be lane-linear (base + lane*16).
__device__ __forceinline__ void gl_lds16(const u16* g, u16* l) {
    __builtin_amdgcn_global_load_lds(
        (const __attribute__((address_space(1))) unsigned*)g,
        (__attribute__((address_space(3))) unsigned*)l, 16, 0, 0);
}

// -------- all-weights transpose + fp32->bf16 convert, single dispatch --------
__global__ __launch_bounds__(256) void transpose_cvt_all(
    const float* __restrict__ Wq, const float* __restrict__ Wk,
    const float* __restrict__ Wv, const float* __restrict__ Wo,
    const float* __restrict__ W1, const float* __restrict__ W2,
    u16* __restrict__ wqt, u16* __restrict__ wkt, u16* __restrict__ wvt,
    u16* __restrict__ wot, u16* __restrict__ w1t, u16* __restrict__ w2t)
{
    __shared__ float tile[64][65];
    int fb = blockIdx.x;
    const float* src; u16* dst; int K, N, bx, by;
    if (fb < 256) {
        int w = fb >> 6, b = fb & 63;
        src = (w == 0) ? Wq : (w == 1) ? Wk : (w == 2) ? Wv : Wo;
        dst = (w == 0) ? wqt : (w == 1) ? wkt : (w == 2) ? wvt : wot;
        K = 512; N = 512; bx = b & 7; by = b >> 3;
    } else if (fb < 512) {
        int b = fb - 256; src = W1; dst = w1t; K = 512; N = 2048; bx = b & 31; by = b >> 5;
    } else {
        int b = fb - 512; src = W2; dst = w2t; K = 2048; N = 512; bx = b & 7; by = b >> 3;
    }
    int n0 = bx * 64, k0 = by * 64;
    int tx = threadIdx.x & 63, ty = threadIdx.x >> 6;
    #pragma unroll
    for (int i = ty; i < 64; i += 4)
        tile[i][tx] = src[(size_t)(k0 + i) * N + n0 + tx];
    __syncthreads();
    #pragma unroll
    for (int i = ty; i < 64; i += 4)
        dst[(size_t)(n0 + i) * K + k0 + tx] = f2bf(tile[tx][i]);
}

// ---------------- layernorm: fp32 in -> bf16 out, rows of 512 ----------------
__global__ __launch_bounds__(256) void ln_kernel(const float* __restrict__ in,
                                                 u16* __restrict__ out,
                                                 const float* __restrict__ g,
                                                 const float* __restrict__ b) {
    int row = blockIdx.x;
    const float* rp = in + (size_t)row * 512;
    int t = threadIdx.x;
    float2 v = *(const float2*)(rp + t * 2);
    float s = v.x + v.y;
    float sq = v.x * v.x + v.y * v.y;
    #pragma unroll
    for (int off = 32; off > 0; off >>= 1) {
        s  += __shfl_down(s, off, 64);
        sq += __shfl_down(sq, off, 64);
    }
    __shared__ float red[8];
    __shared__ float stat[2];
    int wid = t >> 6;
    if ((t & 63) == 0) { red[wid] = s; red[wid + 4] = sq; }
    __syncthreads();
    if (t == 0) {
        float S = red[0] + red[1] + red[2] + red[3];
        float Q = red[4] + red[5] + red[6] + red[7];
        float mu = S * (1.0f / 512.0f);
        float var = Q * (1.0f / 512.0f) - mu * mu;
        stat[0] = mu;
        stat[1] = rsqrtf(var + 1e-5f);
    }
    __syncthreads();
    float mu = stat[0], inv = stat[1];
    int c = t * 2;
    float2 gv = *(const float2*)(g + c);
    float2 bv = *(const float2*)(b + c);
    ushort2 ov;
    ov.x = f2bf((v.x - mu) * inv * gv.x + bv.x);
    ov.y = f2bf((v.y - mu) * inv * gv.y + bv.y);
    *(ushort2*)(out + (size_t)row * 512 + c) = ov;
}

// ================== 256x256 8-phase MFMA GEMM machinery ======================
// (unchanged from round 6 — verified passing)

#define FENCE() asm volatile("" ::: "memory")
#define BARF()  do { FENCE(); __builtin_amdgcn_s_barrier(); FENCE(); } while (0)
#define LGKM0() asm volatile("s_waitcnt lgkmcnt(0)" ::: "memory")
#define VM4()   asm volatile("s_waitcnt vmcnt(4)" ::: "memory")
#define VM0()   asm volatile("s_waitcnt vmcnt(0)" ::: "memory")
#define PRIO1() __builtin_amdgcn_s_setprio(1)
#define PRIO0() __builtin_amdgcn_s_setprio(0)

// swizzled fragment read: region is [128 rows][64 bf16], 16B-aligned groups
__device__ __forceinline__ bf16x8 ldfrag(const u16* __restrict__ base, int R, int ko, int lq) {
    int o = (ko + lq * 8) ^ ((R & 7) * 8);
    return *(const bf16x8*)(base + R * 64 + o);
}

__device__ __forceinline__ void gemm256_core(
    const u16* __restrict__ A, const u16* __restrict__ Bt, int K,
    int m0, int n0, int t, u16* __restrict__ smem, f32x4 (&acc)[8][4])
{
    const int NS = K >> 6;
    const int wid = t >> 6, lane = t & 63;
    const int lm = lane & 15, lq = lane >> 4;
    const int wm_ = wid >> 2;            // warp_m: A region
    const int wn_ = wid & 3;             // warp_n
    const int wbh = wn_ >> 1;            // B region
    const int wbr = (wn_ & 1) * 64;      // row offset within B region

    auto reg = [&](int buf, int ab, int half) -> u16* {
        return smem + (((buf << 1) | ab) * 2 + half) * 8192;
    };

    const int r0 = t >> 3;                               // 0..63
    const int csw = ((t & 7) * 8) ^ ((r0 & 7) * 8);      // inverse-swizzled col
    const u16* gA = A + (size_t)(m0 + r0) * K + csw;
    const u16* gB = Bt + (size_t)(n0 + r0) * K + csw;
    const size_t pK64 = (size_t)64 * K;
    const size_t hK128 = (size_t)128 * K;

    auto stA = [&](int u, int hf) {
        if (u >= NS) return;
        u16* d = reg(u & 1, 0, hf) + t * 8;
        const u16* s = gA + (size_t)(u * 64) + (hf ? hK128 : (size_t)0);
        gl_lds16(s, d);
        gl_lds16(s + pK64, d + 4096);
    };
    auto stB = [&](int u, int hf) {
        if (u >= NS) return;
        u16* d = reg(u & 1, 1, hf) + t * 8;
        const u16* s = gB + (size_t)(u * 64) + (hf ? hK128 : (size_t)0);
        gl_lds16(s, d);
        gl_lds16(s + pK64, d + 4096);
    };

    #pragma unroll
    for (int i = 0; i < 8; ++i)
        #pragma unroll
        for (int j = 0; j < 4; ++j) acc[i][j] = (f32x4){0.f, 0.f, 0.f, 0.f};

    stB(0, 0); stB(0, 1); stA(0, 0); stA(0, 1);
    stB(1, 0); stB(1, 1);
    VM4();
    BARF();

    for (int s = 0; s < NS; ++s) {
        const u16* As = reg(s & 1, 0, wm_);
        const u16* Bs = reg(s & 1, 1, wbh);
        bf16x8 aF[4], bF[4][2];
        // ---- phase 0: read A-lo-k0 (4) + B-k0 (4); stage Alo+Ahi(s+1) ----
        #pragma unroll
        for (int i = 0; i < 4; ++i) aF[i] = ldfrag(As, i * 16 + lm, 0, lq);
        #pragma unroll
        for (int j = 0; j < 4; ++j) bF[j][0] = ldfrag(Bs, wbr + j * 16 + lm, 0, lq);
        stA(s + 1, 0);
        stA(s + 1, 1);
        BARF(); PRIO1();
        #pragma unroll
        for (int i = 0; i < 4; ++i)
            #pragma unroll
            for (int j = 0; j < 4; ++j)
                acc[i][j] = MFMA16(aF[i], bF[j][0], acc[i][j]);
        PRIO0(); LGKM0(); BARF();
        // ---- phase 1: read A-lo-k1 (4) + B-k1 (4); no stage ----
        #pragma unroll
        for (int i = 0; i < 4; ++i) aF[i] = ldfrag(As, i * 16 + lm, 32, lq);
        #pragma unroll
        for (int j = 0; j < 4; ++j) bF[j][1] = ldfrag(Bs, wbr + j * 16 + lm, 32, lq);
        BARF(); PRIO1();
        #pragma unroll
        for (int i = 0; i < 4; ++i)
            #pragma unroll
            for (int j = 0; j < 4; ++j)
                acc[i][j] = MFMA16(aF[i], bF[j][1], acc[i][j]);
        PRIO0(); LGKM0(); BARF();
        // ---- phase 2: read A-hi-k0 (4); stage Blo(s+2) ----
        #pragma unroll
        for (int i = 0; i < 4; ++i) aF[i] = ldfrag(As, 64 + i * 16 + lm, 0, lq);
        stB(s + 2, 0);
        BARF(); PRIO1();
        #pragma unroll
        for (int i = 0; i < 4; ++i)
            #pragma unroll
            for (int j = 0; j < 4; ++j)
                acc[4 + i][j] = MFMA16(aF[i], bF[j][0], acc[4 + i][j]);
        PRIO0(); LGKM0(); BARF();
        // ---- phase 3: read A-hi-k1 (4); stage Bhi(s+2); vmcnt ----
        #pragma unroll
        for (int i = 0; i < 4; ++i) aF[i] = ldfrag(As, 64 + i * 16 + lm, 32, lq);
        stB(s + 2, 1);
        BARF(); PRIO1();
        #pragma unroll
        for (int i = 0; i < 4; ++i)
            #pragma unroll
            for (int j = 0; j < 4; ++j)
                acc[4 + i][j] = MFMA16(aF[i], bF[j][1], acc[4 + i][j]);
        PRIO0(); LGKM0();
        if (s >= NS - 2) { VM0(); } else { VM4(); }
        BARF();
    }
}

// ======== fused QKV: 256x256 tiles, 6 n-tiles (2 q | 2 k | 2 v) =============
__global__ __launch_bounds__(512) void qkv256_kernel(
    const u16* __restrict__ A,
    const u16* __restrict__ wqt, const u16* __restrict__ wkt, const u16* __restrict__ wvt,
    const float* __restrict__ bqp, const float* __restrict__ bkp, const float* __restrict__ bvp,
    u16* __restrict__ qb, u16* __restrict__ kb, u16* __restrict__ vb, float sclq)
{
    __shared__ u16 smem[65536];            // 128 KiB static
    int flat = blockIdx.x;                 // 768 blocks
    int xcd = flat & 7, slot = flat >> 3;
    int g = xcd * 96 + slot;               // bijective (768 % 8 == 0)
    int mt = g / 6, nt = g % 6;
    int mode = nt >> 1;                    // 0=q 1=k 2=v
    int m0 = mt * 256, nb0 = (nt & 1) * 256;
    const u16* Bt = (mode == 0) ? wqt : (mode == 1) ? wkt : wvt;
    const float* bias = (mode == 0) ? bqp : (mode == 1) ? bkp : bvp;
    u16* outp = (mode == 0) ? qb : (mode == 1) ? kb : vb;

    int t = threadIdx.x;
    f32x4 acc[8][4];
    gemm256_core(A, Bt, 512, m0, nb0, t, smem, acc);

    int wid = t >> 6, lane = t & 63, lm = lane & 15, lq = lane >> 4;
    int rowb = m0 + (wid >> 2) * 128;
    int colb = nb0 + (wid & 3) * 64;       // one 64-wide head per wave

    if (mode < 2) {   // q/k: RoPE + head layout [bc][h][s][d]
        float bv0 = bias[colb + 0 * 16 + lm];
        float bv1 = bias[colb + 1 * 16 + lm];
        float bv2 = bias[colb + 2 * 16 + lm];
        float bv3 = bias[colb + 3 * 16 + lm];
        float its = __expf((float)lm * -0.28782313662425572f);  // 10000^(-lm/32)
        float scl = (mode == 0) ? sclq : 1.f;
        #pragma unroll
        for (int i = 0; i < 8; ++i) {
            #pragma unroll
            for (int r = 0; r < 4; ++r) {
                int gm = rowb + i * 16 + lq * 4 + r;
                int s = gm & 511;
                float ang = (float)s * its;
                float sn = __sinf(ang), cs = __cosf(ang);
                float x1 = acc[i][0][r] + bv0;
                float x2 = acc[i][2][r] + bv2;
                float y0 = (x1 * cs - x2 * sn) * scl;
                float y2 = (x2 * cs + x1 * sn) * scl;
                float y1 = (acc[i][1][r] + bv1) * scl;
                float y3 = (acc[i][3][r] + bv3) * scl;
                size_t base = ((size_t)(gm >> 9)) * 262144 + (size_t)(colb >> 6) * 32768
                            + (size_t)s * 64 + lm;
                outp[base +  0] = f2bf(y0);
                outp[base + 16] = f2bf(y1);
                outp[base + 32] = f2bf(y2);
                outp[base + 48] = f2bf(y3);
            }
        }
    } else {          // v: transposed head layout [bc][h][d][s]
        #pragma unroll
        for (int i = 0; i < 8; ++i)
            #pragma unroll
            for (int j = 0; j < 4; ++j) {
                int gn = colb + j * 16 + lm;
                float bvv = bias[gn];
                #pragma unroll
                for (int r = 0; r < 4; ++r) {
                    int gm = rowb + i * 16 + lq * 4 + r;
                    float v = acc[i][j][r] + bvv;
                    size_t idx = ((size_t)(gm >> 9)) * 262144 + (size_t)(gn >> 6) * 32768
                               + (size_t)(gn & 63) * 512 + (gm & 511);
                    outp[idx] = f2bf(v);
                }
            }
    }
}

// -------- generic 256x256 8-phase GEMM --------
// MODE 3: out fp32 row-major, v=acc+bias+res ; MODE 4: out bf16, v=gelu(acc+bias)
template<int MODE>
__global__ __launch_bounds__(512) void gemm256_kernel(
    const u16* __restrict__ A, const u16* __restrict__ Bt,
    const float* __restrict__ bias, const float* __restrict__ res,
    void* __restrict__ outp, int M, int N, int K)
{
    __shared__ u16 smem[65536];            // 128 KiB static
    int flat = blockIdx.x;
    int nbt = N >> 8;
    int nwg = (M >> 8) * nbt;
    int xcd = flat & 7, slot = flat >> 3;
    int g = xcd * (nwg >> 3) + slot;       // grids are multiples of 8
    int mt = g / nbt, nt = g % nbt;
    int m0 = mt * 256, n0 = nt * 256;

    int t = threadIdx.x;
    f32x4 acc[8][4];
    gemm256_core(A, Bt, K, m0, n0, t, smem, acc);

    int wid = t >> 6, lane = t & 63, lm = lane & 15, lq = lane >> 4;
    int rowb = m0 + (wid >> 2) * 128, colb = n0 + (wid & 3) * 64;
    #pragma unroll
    for (int i = 0; i < 8; ++i)
        #pragma unroll
        for (int j = 0; j < 4; ++j) {
            int gn = colb + j * 16 + lm;
            float bv = bias[gn];
            #pragma unroll
            for (int r = 0; r < 4; ++r) {
                int gm = rowb + i * 16 + lq * 4 + r;
                float v = acc[i][j][r] + bv;
                if (MODE == 3) {
                    size_t idx = (size_t)gm * N + gn;
                    ((float*)outp)[idx] = v + res[idx];
                } else {
                    ((u16*)outp)[(size_t)gm * N + gn] = f2bf(fgelu(v));
                }
            }
        }
}

// ---------------- flash attention, transposed-S, 4 q-subtiles per stage ------
// v2: K/V staged via global_load_lds (XOR-swizzled source, linear dest,
// double-buffered, DMA issued for kt+1 before computing kt); V fragments
// read inline in the PV loop (no aV hoist, -32 VGPR); pv folded into sc
// (-16 VGPR); defer-max (skip O-rescale when __all(mx <= mo+8));
// __launch_bounds__(256,3) pins 3 waves/SIMD.
__global__ __launch_bounds__(256, 3) void attn_kernel(
    const u16* __restrict__ q, const u16* __restrict__ k,
    const u16* __restrict__ vt, u16* __restrict__ o)
{
    int flat = blockIdx.y * gridDim.x + blockIdx.x;   // grid (2,512) = 1024 blocks
    int xcd = flat & 7, slot = flat >> 3;
    int nh = xcd * 64 + (slot >> 1);
    int qt = slot & 1;
    const u16* Qb = q + (size_t)nh * 32768 + (size_t)qt * 16384;
    const u16* Kb = k + (size_t)nh * 32768;
    const u16* Vb = vt + (size_t)nh * 32768;
    __shared__ u16 sKV[2][2][4096];    // [buf][K/V][64x64 swizzled]
    __shared__ u16 lP[4][16][72];
    int t = threadIdx.x, wid = t >> 6, lane = t & 63, lm = lane & 15, lq = lane >> 4;

    // staging addresses (2 chunks each of K and V per thread)
    auto stKV = [&](int kt, int buf) {
        if (kt >= 8) return;
        #pragma unroll
        for (int p = 0; p < 2; ++p) {
            int idx = p * 256 + t;
            int row = idx >> 3;
            int c = ((idx & 7) * 8) ^ ((row & 7) * 8);   // inverse-swizzled col
            gl_lds16(Kb + (size_t)(kt * 64 + row) * 64 + c, &sKV[buf][0][idx * 8]);
            gl_lds16(Vb + (size_t)row * 512 + kt * 64 + c, &sKV[buf][1][idx * 8]);
        }
    };
    // swizzled read: storage[row][c] holds global[row][c ^ ((row&7)*8)]
    auto ldsw = [&](const u16* base, int row, int cu16) -> bf16x8 {
        return *(const bf16x8*)&base[row * 64 + (cu16 ^ ((row & 7) * 8))];
    };

    bf16x8 bq[4][2];
    #pragma unroll
    for (int sub = 0; sub < 4; ++sub) {
        const u16* qr = Qb + (size_t)(sub * 64 + wid * 16 + lm) * 64;
        bq[sub][0] = *(const bf16x8*)(qr + lq * 8);
        bq[sub][1] = *(const bf16x8*)(qr + 32 + lq * 8);
    }

    const f32x4 zero = {0.f, 0.f, 0.f, 0.f};
    f32x4 Oacc[4][4];
    float mo[4], l[4];
    #pragma unroll
    for (int s = 0; s < 4; ++s) {
        mo[s] = -INFINITY; l[s] = 0.f;
        #pragma unroll
        for (int d = 0; d < 4; ++d) Oacc[s][d] = zero;
    }

    stKV(0, 0);
    VM0(); BARF();

    for (int kt = 0; kt < 8; ++kt) {
        int buf = kt & 1;
        stKV(kt + 1, buf ^ 1);            // DMA next tile under this tile's compute
        const u16* Kl = sKV[buf][0];
        const u16* Vl = sKV[buf][1];
        bf16x8 aK[4][2];
        #pragma unroll
        for (int i = 0; i < 4; ++i) {
            aK[i][0] = ldsw(Kl, i * 16 + lm, lq * 8);
            aK[i][1] = ldsw(Kl, i * 16 + lm, 32 + lq * 8);
        }
        #pragma unroll
        for (int sub = 0; sub < 4; ++sub) {
            f32x4 sc[4];
            #pragma unroll
            for (int i = 0; i < 4; ++i) {
                f32x4 z = MFMA16(aK[i][0], bq[sub][0], zero);
                sc[i] = MFMA16(aK[i][1], bq[sub][1], z);
            }
            float mx = sc[0][0];
            #pragma unroll
            for (int i = 0; i < 4; ++i)
                #pragma unroll
                for (int r = 0; r < 4; ++r) mx = fmaxf(mx, sc[i][r]);
            mx = fmaxf(mx, __shfl_xor(mx, 16, 64));
            mx = fmaxf(mx, __shfl_xor(mx, 32, 64));
            // defer-max: skip rescale while max growth <= 8 (P bounded by 2^8)
            if (!__all(mx <= mo[sub] + 8.0f)) {
                float mn = fmaxf(mo[sub], mx);
                float al = fexp2(mo[sub] - mn);
                l[sub] *= al;
                #pragma unroll
                for (int dn = 0; dn < 4; ++dn) Oacc[sub][dn] *= al;
                mo[sub] = mn;
            }
            float mc = mo[sub];
            float sum = 0.f;
            #pragma unroll
            for (int i = 0; i < 4; ++i)
                #pragma unroll
                for (int r = 0; r < 4; ++r) {
                    float p = fexp2(sc[i][r] - mc);
                    sc[i][r] = p;
                    sum += p;
                }
            sum += __shfl_xor(sum, 16, 64);
            sum += __shfl_xor(sum, 32, 64);
            l[sub] += sum;
            #pragma unroll
            for (int i = 0; i < 4; ++i) {
                uint2 w2;
                w2.x = pack_bf16(sc[i][0], sc[i][1]);
                w2.y = pack_bf16(sc[i][2], sc[i][3]);
                *(uint2*)&lP[wid][lm][i * 16 + lq * 4] = w2;
            }
            bf16x8 bp0 = *(const bf16x8*)&lP[wid][lm][lq * 8];
            bf16x8 bp1 = *(const bf16x8*)&lP[wid][lm][32 + lq * 8];
            #pragma unroll
            for (int dn = 0; dn < 4; ++dn) {
                bf16x8 v0 = ldsw(Vl, dn * 16 + lm, lq * 8);
                bf16x8 v1 = ldsw(Vl, dn * 16 + lm, 32 + lq * 8);
                Oacc[sub][dn] = MFMA16(v0, bp0, Oacc[sub][dn]);
                Oacc[sub][dn] = MFMA16(v1, bp1, Oacc[sub][dn]);
            }
        }
        LGKM0(); VM0(); BARF();           // reads done + next-tile DMA landed
    }
    int bc = nh >> 3, h = nh & 7;
    #pragma unroll
    for (int sub = 0; sub < 4; ++sub) {
        float inv = 1.f / l[sub];
        size_t orow = ((size_t)(bc * 512 + qt * 256 + sub * 64 + wid * 16 + lm)) * 512 + h * 64;
        #pragma unroll
        for (int dn = 0; dn < 4; ++dn) {
            uint2 w2;
            w2.x = pack_bf16(Oacc[sub][dn][0] * inv, Oacc[sub][dn][1] * inv);
            w2.y = pack_bf16(Oacc[sub][dn][2] * inv, Oacc[sub][dn][3] * inv);
            *(uint2*)(o + orow + dn * 16 + lq * 4) = w2;
        }
    }
}

extern "C" void kernel_launch(void* const* d_in, const int* in_sizes, int n_in,
                              void* d_out, int out_size, void* d_ws, size_t ws_size,
                              hipStream_t stream) {
    const float* x    = (const float*)d_in[0];
    const float* Wq   = (const float*)d_in[1];
    const float* bq   = (const float*)d_in[2];
    const float* Wk   = (const float*)d_in[3];
    const float* bk   = (const float*)d_in[4];
    const float* Wv   = (const float*)d_in[5];
    const float* bv   = (const float*)d_in[6];
    const float* Wo   = (const float*)d_in[7];
    const float* bo   = (const float*)d_in[8];
    const float* ln1g = (const float*)d_in[9];
    const float* ln1b = (const float*)d_in[10];
    const float* ln3g = (const float*)d_in[11];
    const float* ln3b = (const float*)d_in[12];
    const float* W1   = (const float*)d_in[13];
    const float* b1   = (const float*)d_in[14];
    const float* W2   = (const float*)d_in[15];
    const float* b2   = (const float*)d_in[16];

    char* ws = (char*)d_ws;
    u16*  hn  = (u16*)(ws + 0ull);            // 33,554,432  (also hn2)
    u16*  qb  = (u16*)(ws + 33554432ull);     // 33,554,432
    u16*  kb  = (u16*)(ws + 67108864ull);     // 33,554,432
    u16*  vb  = (u16*)(ws + 100663296ull);    // 33,554,432
    u16*  ob  = (u16*)(ws + 134217728ull);    // 33,554,432
    u16*  ffa = (u16*)(ws + 33554432ull);     // 134,217,728 (after o consumed)
    float* h1 = (float*)(ws + 167772160ull);  // 67,108,864
    u16*  wqt = (u16*)(ws + 234881024ull);
    u16*  wkt = (u16*)(ws + 235405312ull);
    u16*  wvt = (u16*)(ws + 235929600ull);
    u16*  wot = (u16*)(ws + 236453888ull);
    u16*  w1t = (u16*)(ws + 236978176ull);    // 2,097,152
    u16*  w2t = (u16*)(ws + 239075328ull);    // 2,097,152

    dim3 blk(256);
    transpose_cvt_all<<<768, blk, 0, stream>>>(Wq, Wk, Wv, Wo, W1, W2,
                                               wqt, wkt, wvt, wot, w1t, w2t);

    ln_kernel<<<32768, blk, 0, stream>>>(x, hn, ln1g, ln1b);

    // q scale folds HD^-0.5 and log2(e) (softmax computed base-2)
    qkv256_kernel<<<768, dim3(512), 0, stream>>>(hn, wqt, wkt, wvt, bq, bk, bv,
                                                 qb, kb, vb,
                                                 0.125f * 1.4426950408889634f);

    attn_kernel<<<dim3(2, 512), blk, 0, stream>>>(qb, kb, vb, ob);

    gemm256_kernel<3><<<256, dim3(512), 0, stream>>>(ob, wot, bo, x, h1,
                                                     32768, 512, 512);

    ln_kernel<<<32768, blk, 0, stream>>>(h1, hn, ln3g, ln3b);

    gemm256_kernel<4><<<1024, dim3(512), 0, stream>>>(hn, w1t, b1, nullptr, ffa,
                                                      32768, 2048, 512);
    gemm256_kernel<3><<<256, dim3(512), 0, stream>>>(ffa, w2t, b2, h1,
                                                     (float*)d_out, 32768, 512, 2048);
}

// Round 8
// 537.288 us; speedup vs baseline: 1.1208x; 1.0216x over previous
//
#include <hip/hip_runtime.h>
#include <math.h>

typedef unsigned short u16;
typedef __attribute__((ext_vector_type(8))) short bf16x8;
typedef __attribute__((ext_vector_type(4))) float f32x4;

#define MFMA16(a, b, c) __builtin_amdgcn_mfma_f32_16x16x32_bf16((a), (b), (c), 0, 0, 0)

__device__ __forceinline__ u16 f2bf(float f) {
    union { float f; unsigned u; } v; v.f = f;
    unsigned u = v.u;
    unsigned r = (u + 0x7FFFu + ((u >> 16) & 1u)) >> 16;
    return (u16)r;
}

// pack two floats -> (bf16(hi)<<16)|bf16(lo), round-half-up, one v_perm_b32
__device__ __forceinline__ unsigned pack_bf16(float lo, float hi) {
    union { float f; unsigned u; } a, b; a.f = lo; b.f = hi;
    return __builtin_amdgcn_perm(b.u + 0x8000u, a.u + 0x8000u, 0x07060302u);
}

__device__ __forceinline__ float fexp2(float x) {
#if __has_builtin(__builtin_amdgcn_exp2f)
    return __builtin_amdgcn_exp2f(x);
#else
    return __expf(x * 0.6931471805599453f);
#endif
}

__device__ __forceinline__ float frcp(float x) {
#if __has_builtin(__builtin_amdgcn_rcpf)
    return __builtin_amdgcn_rcpf(x);
#else
    return 1.0f / x;
#endif
}

// tanh-form GELU via exp2+rcp: ~7 VALU ops vs ~30+ for erff.
__device__ __forceinline__ float fgelu(float v) {
    float x2 = v * v;
    float u = v * (0.7978845608028654f + 0.035677408136300125f * x2);
    return v * frcp(1.0f + fexp2(-2.8853900817779268f * u));
}

// async 16B/lane global->LDS DMA. LDS dest must be lane-linear (base + lane*16).
__device__ __forceinline__ void gl_lds16(const u16* g, u16* l) {
    __builtin_amdgcn_global_load_lds(
        (const __attribute__((address_space(1))) unsigned*)g,
        (__attribute__((address_space(3))) unsigned*)l, 16, 0, 0);
}

// -------- all-weights transpose + fp32->bf16 convert, single dispatch --------
__global__ __launch_bounds__(256) void transpose_cvt_all(
    const float* __restrict__ Wq, const float* __restrict__ Wk,
    const float* __restrict__ Wv, const float* __restrict__ Wo,
    const float* __restrict__ W1, const float* __restrict__ W2,
    u16* __restrict__ wqt, u16* __restrict__ wkt, u16* __restrict__ wvt,
    u16* __restrict__ wot, u16* __restrict__ w1t, u16* __restrict__ w2t)
{
    __shared__ float tile[64][65];
    int fb = blockIdx.x;
    const float* src; u16* dst; int K, N, bx, by;
    if (fb < 256) {
        int w = fb >> 6, b = fb & 63;
        src = (w == 0) ? Wq : (w == 1) ? Wk : (w == 2) ? Wv : Wo;
        dst = (w == 0) ? wqt : (w == 1) ? wkt : (w == 2) ? wvt : wot;
        K = 512; N = 512; bx = b & 7; by = b >> 3;
    } else if (fb < 512) {
        int b = fb - 256; src = W1; dst = w1t; K = 512; N = 2048; bx = b & 31; by = b >> 5;
    } else {
        int b = fb - 512; src = W2; dst = w2t; K = 2048; N = 512; bx = b & 7; by = b >> 3;
    }
    int n0 = bx * 64, k0 = by * 64;
    int tx = threadIdx.x & 63, ty = threadIdx.x >> 6;
    #pragma unroll
    for (int i = ty; i < 64; i += 4)
        tile[i][tx] = src[(size_t)(k0 + i) * N + n0 + tx];
    __syncthreads();
    #pragma unroll
    for (int i = ty; i < 64; i += 4)
        dst[(size_t)(n0 + i) * K + k0 + tx] = f2bf(tile[tx][i]);
}

// ---------------- layernorm: fp32 in -> bf16 out, rows of 512 ----------------
__global__ __launch_bounds__(256) void ln_kernel(const float* __restrict__ in,
                                                 u16* __restrict__ out,
                                                 const float* __restrict__ g,
                                                 const float* __restrict__ b) {
    int row = blockIdx.x;
    const float* rp = in + (size_t)row * 512;
    int t = threadIdx.x;
    float2 v = *(const float2*)(rp + t * 2);
    float s = v.x + v.y;
    float sq = v.x * v.x + v.y * v.y;
    #pragma unroll
    for (int off = 32; off > 0; off >>= 1) {
        s  += __shfl_down(s, off, 64);
        sq += __shfl_down(sq, off, 64);
    }
    __shared__ float red[8];
    __shared__ float stat[2];
    int wid = t >> 6;
    if ((t & 63) == 0) { red[wid] = s; red[wid + 4] = sq; }
    __syncthreads();
    if (t == 0) {
        float S = red[0] + red[1] + red[2] + red[3];
        float Q = red[4] + red[5] + red[6] + red[7];
        float mu = S * (1.0f / 512.0f);
        float var = Q * (1.0f / 512.0f) - mu * mu;
        stat[0] = mu;
        stat[1] = rsqrtf(var + 1e-5f);
    }
    __syncthreads();
    float mu = stat[0], inv = stat[1];
    int c = t * 2;
    float2 gv = *(const float2*)(g + c);
    float2 bv = *(const float2*)(b + c);
    ushort2 ov;
    ov.x = f2bf((v.x - mu) * inv * gv.x + bv.x);
    ov.y = f2bf((v.y - mu) * inv * gv.y + bv.y);
    *(ushort2*)(out + (size_t)row * 512 + c) = ov;
}

// ================== 256x256 MFMA GEMM, minimal-sync schedule =================
// BM=BN=256, BK=64, 512 threads = 8 waves (2M x 4N), per-wave out 128x64.
// LDS 128 KiB STATIC: [buf2][A/B][region2][128x64 bf16]. XOR-swizzle
// byte^=(row&7)<<4 via inverse-swizzled GLOBAL source + swizzled ds_read.
// MINIMAL SYNC SET (derived round 8):
//  - B-region WAR: B(s) reads done by ph1 -> one LGKM0+BAR at MID-STEP gates
//    stB(s+2,*) issued in the second half-step (same buffer).
//  - A-region WAR: A(s) reads done by ph3 -> step-end LGKM0+BAR gates
//    stA(s+2) issued at ph0 of step s+1.  stA(s+1) writes the OPPOSITE
//    buffer - safe by construction.
//  - DMA RAW: VM4+BAR at step end retires B(s+1)+A(s+1) (FIFO: 4 old B,
//    4 new A, 4 new B); barrier needed because each wave stages only 1/8
//    of each region.  VM0 on the last two steps.
// No pre-MFMA barriers: each wave enters MFMA on its own counted lgkm
// waits, so wave i's MFMA overlaps wave j's ds_reads (m114 overlap).

#define FENCE() asm volatile("" ::: "memory")
#define BARF()  do { FENCE(); __builtin_amdgcn_s_barrier(); FENCE(); } while (0)
#define LGKM0() asm volatile("s_waitcnt lgkmcnt(0)" ::: "memory")
#define VM4()   asm volatile("s_waitcnt vmcnt(4)" ::: "memory")
#define VM0()   asm volatile("s_waitcnt vmcnt(0)" ::: "memory")
#define PRIO1() __builtin_amdgcn_s_setprio(1)
#define PRIO0() __builtin_amdgcn_s_setprio(0)

// swizzled fragment read: region is [128 rows][64 bf16], 16B-aligned groups
__device__ __forceinline__ bf16x8 ldfrag(const u16* __restrict__ base, int R, int ko, int lq) {
    int o = (ko + lq * 8) ^ ((R & 7) * 8);
    return *(const bf16x8*)(base + R * 64 + o);
}

__device__ __forceinline__ void gemm256_core(
    const u16* __restrict__ A, const u16* __restrict__ Bt, int K,
    int m0, int n0, int t, u16* __restrict__ smem, f32x4 (&acc)[8][4])
{
    const int NS = K >> 6;
    const int wid = t >> 6, lane = t & 63;
    const int lm = lane & 15, lq = lane >> 4;
    const int wm_ = wid >> 2;            // warp_m: A region
    const int wn_ = wid & 3;             // warp_n
    const int wbh = wn_ >> 1;            // B region
    const int wbr = (wn_ & 1) * 64;      // row offset within B region

    auto reg = [&](int buf, int ab, int half) -> u16* {
        return smem + (((buf << 1) | ab) * 2 + half) * 8192;
    };

    const int r0 = t >> 3;                               // 0..63
    const int csw = ((t & 7) * 8) ^ ((r0 & 7) * 8);      // inverse-swizzled col
    const u16* gA = A + (size_t)(m0 + r0) * K + csw;
    const u16* gB = Bt + (size_t)(n0 + r0) * K + csw;
    const size_t pK64 = (size_t)64 * K;
    const size_t hK128 = (size_t)128 * K;

    auto stA = [&](int u, int hf) {
        if (u >= NS) return;
        u16* d = reg(u & 1, 0, hf) + t * 8;
        const u16* s = gA + (size_t)(u * 64) + (hf ? hK128 : (size_t)0);
        gl_lds16(s, d);
        gl_lds16(s + pK64, d + 4096);
    };
    auto stB = [&](int u, int hf) {
        if (u >= NS) return;
        u16* d = reg(u & 1, 1, hf) + t * 8;
        const u16* s = gB + (size_t)(u * 64) + (hf ? hK128 : (size_t)0);
        gl_lds16(s, d);
        gl_lds16(s + pK64, d + 4096);
    };

    #pragma unroll
    for (int i = 0; i < 8; ++i)
        #pragma unroll
        for (int j = 0; j < 4; ++j) acc[i][j] = (f32x4){0.f, 0.f, 0.f, 0.f};

    // prologue: tile0 fully (issued first) + B(1); VM4 retires exactly tile0
    stB(0, 0); stB(0, 1); stA(0, 0); stA(0, 1);
    stB(1, 0); stB(1, 1);
    VM4();
    BARF();

    for (int s = 0; s < NS; ++s) {
        const u16* As = reg(s & 1, 0, wm_);
        const u16* Bs = reg(s & 1, 1, wbh);
        bf16x8 aF[4], bF[4][2];
        // ======== half-step A (A-lo rows, both K-slices) ========
        #pragma unroll
        for (int i = 0; i < 4; ++i) aF[i] = ldfrag(As, i * 16 + lm, 0, lq);
        #pragma unroll
        for (int j = 0; j < 4; ++j) bF[j][0] = ldfrag(Bs, wbr + j * 16 + lm, 0, lq);
        stA(s + 1, 0);
        stA(s + 1, 1);
        PRIO1();
        #pragma unroll
        for (int i = 0; i < 4; ++i)
            #pragma unroll
            for (int j = 0; j < 4; ++j)
                acc[i][j] = MFMA16(aF[i], bF[j][0], acc[i][j]);
        PRIO0();
        #pragma unroll
        for (int i = 0; i < 4; ++i) aF[i] = ldfrag(As, i * 16 + lm, 32, lq);
        #pragma unroll
        for (int j = 0; j < 4; ++j) bF[j][1] = ldfrag(Bs, wbr + j * 16 + lm, 32, lq);
        PRIO1();
        #pragma unroll
        for (int i = 0; i < 4; ++i)
            #pragma unroll
            for (int j = 0; j < 4; ++j)
                acc[i][j] = MFMA16(aF[i], bF[j][1], acc[i][j]);
        PRIO0();
        LGKM0(); BARF();          // all B reads drained -> B regions overwritable
        // ======== half-step B (A-hi rows, both K-slices) ========
        #pragma unroll
        for (int i = 0; i < 4; ++i) aF[i] = ldfrag(As, 64 + i * 16 + lm, 0, lq);
        stB(s + 2, 0);
        PRIO1();
        #pragma unroll
        for (int i = 0; i < 4; ++i)
            #pragma unroll
            for (int j = 0; j < 4; ++j)
                acc[4 + i][j] = MFMA16(aF[i], bF[j][0], acc[4 + i][j]);
        PRIO0();
        #pragma unroll
        for (int i = 0; i < 4; ++i) aF[i] = ldfrag(As, 64 + i * 16 + lm, 32, lq);
        stB(s + 2, 1);
        PRIO1();
        #pragma unroll
        for (int i = 0; i < 4; ++i)
            #pragma unroll
            for (int j = 0; j < 4; ++j)
                acc[4 + i][j] = MFMA16(aF[i], bF[j][1], acc[4 + i][j]);
        PRIO0();
        LGKM0();
        if (s >= NS - 2) { VM0(); } else { VM4(); }
        BARF();
    }
}

// ======== fused QKV: 256x256 tiles, 6 n-tiles (2 q | 2 k | 2 v) =============
__global__ __launch_bounds__(512) void qkv256_kernel(
    const u16* __restrict__ A,
    const u16* __restrict__ wqt, const u16* __restrict__ wkt, const u16* __restrict__ wvt,
    const float* __restrict__ bqp, const float* __restrict__ bkp, const float* __restrict__ bvp,
    u16* __restrict__ qb, u16* __restrict__ kb, u16* __restrict__ vb, float sclq)
{
    __shared__ u16 smem[65536];            // 128 KiB static
    int flat = blockIdx.x;                 // 768 blocks
    int xcd = flat & 7, slot = flat >> 3;
    int g = xcd * 96 + slot;               // bijective (768 % 8 == 0)
    int mt = g / 6, nt = g % 6;
    int mode = nt >> 1;                    // 0=q 1=k 2=v
    int m0 = mt * 256, nb0 = (nt & 1) * 256;
    const u16* Bt = (mode == 0) ? wqt : (mode == 1) ? wkt : wvt;
    const float* bias = (mode == 0) ? bqp : (mode == 1) ? bkp : bvp;
    u16* outp = (mode == 0) ? qb : (mode == 1) ? kb : vb;

    int t = threadIdx.x;
    f32x4 acc[8][4];
    gemm256_core(A, Bt, 512, m0, nb0, t, smem, acc);

    int wid = t >> 6, lane = t & 63, lm = lane & 15, lq = lane >> 4;
    int rowb = m0 + (wid >> 2) * 128;
    int colb = nb0 + (wid & 3) * 64;       // one 64-wide head per wave

    if (mode < 2) {   // q/k: RoPE + head layout [bc][h][s][d]
        float bv0 = bias[colb + 0 * 16 + lm];
        float bv1 = bias[colb + 1 * 16 + lm];
        float bv2 = bias[colb + 2 * 16 + lm];
        float bv3 = bias[colb + 3 * 16 + lm];
        float its = __expf((float)lm * -0.28782313662425572f);  // 10000^(-lm/32)
        float scl = (mode == 0) ? sclq : 1.f;
        #pragma unroll
        for (int i = 0; i < 8; ++i) {
            #pragma unroll
            for (int r = 0; r < 4; ++r) {
                int gm = rowb + i * 16 + lq * 4 + r;
                int s = gm & 511;
                float ang = (float)s * its;
                float sn = __sinf(ang), cs = __cosf(ang);
                float x1 = acc[i][0][r] + bv0;
                float x2 = acc[i][2][r] + bv2;
                float y0 = (x1 * cs - x2 * sn) * scl;
                float y2 = (x2 * cs + x1 * sn) * scl;
                float y1 = (acc[i][1][r] + bv1) * scl;
                float y3 = (acc[i][3][r] + bv3) * scl;
                size_t base = ((size_t)(gm >> 9)) * 262144 + (size_t)(colb >> 6) * 32768
                            + (size_t)s * 64 + lm;
                outp[base +  0] = f2bf(y0);
                outp[base + 16] = f2bf(y1);
                outp[base + 32] = f2bf(y2);
                outp[base + 48] = f2bf(y3);
            }
        }
    } else {          // v: transposed head layout [bc][h][d][s]
        #pragma unroll
        for (int i = 0; i < 8; ++i)
            #pragma unroll
            for (int j = 0; j < 4; ++j) {
                int gn = colb + j * 16 + lm;
                float bvv = bias[gn];
                #pragma unroll
                for (int r = 0; r < 4; ++r) {
                    int gm = rowb + i * 16 + lq * 4 + r;
                    float v = acc[i][j][r] + bvv;
                    size_t idx = ((size_t)(gm >> 9)) * 262144 + (size_t)(gn >> 6) * 32768
                               + (size_t)(gn & 63) * 512 + (gm & 511);
                    outp[idx] = f2bf(v);
                }
            }
    }
}

// -------- generic 256x256 GEMM --------
// MODE 3: out fp32 row-major, v=acc+bias+res ; MODE 4: out bf16, v=gelu(acc+bias)
template<int MODE>
__global__ __launch_bounds__(512) void gemm256_kernel(
    const u16* __restrict__ A, const u16* __restrict__ Bt,
    const float* __restrict__ bias, const float* __restrict__ res,
    void* __restrict__ outp, int M, int N, int K)
{
    __shared__ u16 smem[65536];            // 128 KiB static
    int flat = blockIdx.x;
    int nbt = N >> 8;
    int nwg = (M >> 8) * nbt;
    int xcd = flat & 7, slot = flat >> 3;
    int g = xcd * (nwg >> 3) + slot;       // grids are multiples of 8
    int mt = g / nbt, nt = g % nbt;
    int m0 = mt * 256, n0 = nt * 256;

    int t = threadIdx.x;
    f32x4 acc[8][4];
    gemm256_core(A, Bt, K, m0, n0, t, smem, acc);

    int wid = t >> 6, lane = t & 63, lm = lane & 15, lq = lane >> 4;
    int rowb = m0 + (wid >> 2) * 128, colb = n0 + (wid & 3) * 64;
    #pragma unroll
    for (int i = 0; i < 8; ++i)
        #pragma unroll
        for (int j = 0; j < 4; ++j) {
            int gn = colb + j * 16 + lm;
            float bv = bias[gn];
            #pragma unroll
            for (int r = 0; r < 4; ++r) {
                int gm = rowb + i * 16 + lq * 4 + r;
                float v = acc[i][j][r] + bv;
                if (MODE == 3) {
                    size_t idx = (size_t)gm * N + gn;
                    ((float*)outp)[idx] = v + res[idx];
                } else {
                    ((u16*)outp)[(size_t)gm * N + gn] = f2bf(fgelu(v));
                }
            }
        }
}

// ---------------- flash attention, transposed-S, 4 q-subtiles per stage ------
// (unchanged from round 7 — verified passing)
__global__ __launch_bounds__(256, 3) void attn_kernel(
    const u16* __restrict__ q, const u16* __restrict__ k,
    const u16* __restrict__ vt, u16* __restrict__ o)
{
    int flat = blockIdx.y * gridDim.x + blockIdx.x;   // grid (2,512) = 1024 blocks
    int xcd = flat & 7, slot = flat >> 3;
    int nh = xcd * 64 + (slot >> 1);
    int qt = slot & 1;
    const u16* Qb = q + (size_t)nh * 32768 + (size_t)qt * 16384;
    const u16* Kb = k + (size_t)nh * 32768;
    const u16* Vb = vt + (size_t)nh * 32768;
    __shared__ u16 sKV[2][2][4096];    // [buf][K/V][64x64 swizzled]
    __shared__ u16 lP[4][16][72];
    int t = threadIdx.x, wid = t >> 6, lane = t & 63, lm = lane & 15, lq = lane >> 4;

    auto stKV = [&](int kt, int buf) {
        if (kt >= 8) return;
        #pragma unroll
        for (int p = 0; p < 2; ++p) {
            int idx = p * 256 + t;
            int row = idx >> 3;
            int c = ((idx & 7) * 8) ^ ((row & 7) * 8);   // inverse-swizzled col
            gl_lds16(Kb + (size_t)(kt * 64 + row) * 64 + c, &sKV[buf][0][idx * 8]);
            gl_lds16(Vb + (size_t)row * 512 + kt * 64 + c, &sKV[buf][1][idx * 8]);
        }
    };
    auto ldsw = [&](const u16* base, int row, int cu16) -> bf16x8 {
        return *(const bf16x8*)&base[row * 64 + (cu16 ^ ((row & 7) * 8))];
    };

    bf16x8 bq[4][2];
    #pragma unroll
    for (int sub = 0; sub < 4; ++sub) {
        const u16* qr = Qb + (size_t)(sub * 64 + wid * 16 + lm) * 64;
        bq[sub][0] = *(const bf16x8*)(qr + lq * 8);
        bq[sub][1] = *(const bf16x8*)(qr + 32 + lq * 8);
    }

    const f32x4 zero = {0.f, 0.f, 0.f, 0.f};
    f32x4 Oacc[4][4];
    float mo[4], l[4];
    #pragma unroll
    for (int s = 0; s < 4; ++s) {
        mo[s] = -INFINITY; l[s] = 0.f;
        #pragma unroll
        for (int d = 0; d < 4; ++d) Oacc[s][d] = zero;
    }

    stKV(0, 0);
    VM0(); BARF();

    for (int kt = 0; kt < 8; ++kt) {
        int buf = kt & 1;
        stKV(kt + 1, buf ^ 1);            // DMA next tile under this tile's compute
        const u16* Kl = sKV[buf][0];
        const u16* Vl = sKV[buf][1];
        bf16x8 aK[4][2];
        #pragma unroll
        for (int i = 0; i < 4; ++i) {
            aK[i][0] = ldsw(Kl, i * 16 + lm, lq * 8);
            aK[i][1] = ldsw(Kl, i * 16 + lm, 32 + lq * 8);
        }
        #pragma unroll
        for (int sub = 0; sub < 4; ++sub) {
            f32x4 sc[4];
            #pragma unroll
            for (int i = 0; i < 4; ++i) {
                f32x4 z = MFMA16(aK[i][0], bq[sub][0], zero);
                sc[i] = MFMA16(aK[i][1], bq[sub][1], z);
            }
            float mx = sc[0][0];
            #pragma unroll
            for (int i = 0; i < 4; ++i)
                #pragma unroll
                for (int r = 0; r < 4; ++r) mx = fmaxf(mx, sc[i][r]);
            mx = fmaxf(mx, __shfl_xor(mx, 16, 64));
            mx = fmaxf(mx, __shfl_xor(mx, 32, 64));
            if (!__all(mx <= mo[sub] + 8.0f)) {
                float mn = fmaxf(mo[sub], mx);
                float al = fexp2(mo[sub] - mn);
                l[sub] *= al;
                #pragma unroll
                for (int dn = 0; dn < 4; ++dn) Oacc[sub][dn] *= al;
                mo[sub] = mn;
            }
            float mc = mo[sub];
            float sum = 0.f;
            #pragma unroll
            for (int i = 0; i < 4; ++i)
                #pragma unroll
                for (int r = 0; r < 4; ++r) {
                    float p = fexp2(sc[i][r] - mc);
                    sc[i][r] = p;
                    sum += p;
                }
            sum += __shfl_xor(sum, 16, 64);
            sum += __shfl_xor(sum, 32, 64);
            l[sub] += sum;
            #pragma unroll
            for (int i = 0; i < 4; ++i) {
                uint2 w2;
                w2.x = pack_bf16(sc[i][0], sc[i][1]);
                w2.y = pack_bf16(sc[i][2], sc[i][3]);
                *(uint2*)&lP[wid][lm][i * 16 + lq * 4] = w2;
            }
            bf16x8 bp0 = *(const bf16x8*)&lP[wid][lm][lq * 8];
            bf16x8 bp1 = *(const bf16x8*)&lP[wid][lm][32 + lq * 8];
            #pragma unroll
            for (int dn = 0; dn < 4; ++dn) {
                bf16x8 v0 = ldsw(Vl, dn * 16 + lm, lq * 8);
                bf16x8 v1 = ldsw(Vl, dn * 16 + lm, 32 + lq * 8);
                Oacc[sub][dn] = MFMA16(v0, bp0, Oacc[sub][dn]);
                Oacc[sub][dn] = MFMA16(v1, bp1, Oacc[sub][dn]);
            }
        }
        LGKM0(); VM0(); BARF();           // reads done + next-tile DMA landed
    }
    int bc = nh >> 3, h = nh & 7;
    #pragma unroll
    for (int sub = 0; sub < 4; ++sub) {
        float inv = 1.f / l[sub];
        size_t orow = ((size_t)(bc * 512 + qt * 256 + sub * 64 + wid * 16 + lm)) * 512 + h * 64;
        #pragma unroll
        for (int dn = 0; dn < 4; ++dn) {
            uint2 w2;
            w2.x = pack_bf16(Oacc[sub][dn][0] * inv, Oacc[sub][dn][1] * inv);
            w2.y = pack_bf16(Oacc[sub][dn][2] * inv, Oacc[sub][dn][3] * inv);
            *(uint2*)(o + orow + dn * 16 + lq * 4) = w2;
        }
    }
}

extern "C" void kernel_launch(void* const* d_in, const int* in_sizes, int n_in,
                              void* d_out, int out_size, void* d_ws, size_t ws_size,
                              hipStream_t stream) {
    const float* x    = (const float*)d_in[0];
    const float* Wq   = (const float*)d_in[1];
    const float* bq   = (const float*)d_in[2];
    const float* Wk   = (const float*)d_in[3];
    const float* bk   = (const float*)d_in[4];
    const float* Wv   = (const float*)d_in[5];
    const float* bv   = (const float*)d_in[6];
    const float* Wo   = (const float*)d_in[7];
    const float* bo   = (const float*)d_in[8];
    const float* ln1g = (const float*)d_in[9];
    const float* ln1b = (const float*)d_in[10];
    const float* ln3g = (const float*)d_in[11];
    const float* ln3b = (const float*)d_in[12];
    const float* W1   = (const float*)d_in[13];
    const float* b1   = (const float*)d_in[14];
    const float* W2   = (const float*)d_in[15];
    const float* b2   = (const float*)d_in[16];

    char* ws = (char*)d_ws;
    u16*  hn  = (u16*)(ws + 0ull);            // 33,554,432  (also hn2)
    u16*  qb  = (u16*)(ws + 33554432ull);     // 33,554,432
    u16*  kb  = (u16*)(ws + 67108864ull);     // 33,554,432
    u16*  vb  = (u16*)(ws + 100663296ull);    // 33,554,432
    u16*  ob  = (u16*)(ws + 134217728ull);    // 33,554,432
    u16*  ffa = (u16*)(ws + 33554432ull);     // 134,217,728 (after o consumed)
    float* h1 = (float*)(ws + 167772160ull);  // 67,108,864
    u16*  wqt = (u16*)(ws + 234881024ull);
    u16*  wkt = (u16*)(ws + 235405312ull);
    u16*  wvt = (u16*)(ws + 235929600ull);
    u16*  wot = (u16*)(ws + 236453888ull);
    u16*  w1t = (u16*)(ws + 236978176ull);    // 2,097,152
    u16*  w2t = (u16*)(ws + 239075328ull);    // 2,097,152

    dim3 blk(256);
    transpose_cvt_all<<<768, blk, 0, stream>>>(Wq, Wk, Wv, Wo, W1, W2,
                                               wqt, wkt, wvt, wot, w1t, w2t);

    ln_kernel<<<32768, blk, 0, stream>>>(x, hn, ln1g, ln1b);

    // q scale folds HD^-0.5 and log2(e) (softmax computed base-2)
    qkv256_kernel<<<768, dim3(512), 0, stream>>>(hn, wqt, wkt, wvt, bq, bk, bv,
                                                 qb, kb, vb,
                                                 0.125f * 1.4426950408889634f);

    attn_kernel<<<dim3(2, 512), blk, 0, stream>>>(qb, kb, vb, ob);

    gemm256_kernel<3><<<256, dim3(512), 0, stream>>>(ob, wot, bo, x, h1,
                                                     32768, 512, 512);

    ln_kernel<<<32768, blk, 0, stream>>>(h1, hn, ln3g, ln3b);

    gemm256_kernel<4><<<1024, dim3(512), 0, stream>>>(hn, w1t, b1, nullptr, ffa,
                                                      32768, 2048, 512);
    gemm256_kernel<3><<<256, dim3(512), 0, stream>>>(ffa, w2t, b2, h1,
                                                     (float*)d_out, 32768, 512, 2048);
}